// Round 2
// baseline (728.626 us; speedup 1.0000x reference)
//
#include <hip/hip_runtime.h>
#include <math.h>

#define ALPHA  0.2f
#define NEGINF -9000000000000000.0f

// ---------------------------------------------------------------------------
// K0: build hamilton (H,512,128) fp32 from W (H,128,128) fp32.
// ham[head][b*128+f0][ob*32+oc] = s(b,ob) * W[head][f0][(b^ob)*32+oc]
// sign negative for (b,ob) in {(1,0),(2,0),(3,0),(2,1),(3,2),(1,3)} -> mask 0x5390
// ---------------------------------------------------------------------------
__global__ __launch_bounds__(256) void k_ham(const float* __restrict__ W,
                                             float* __restrict__ ham) {
    const int base = (blockIdx.x * 256 + threadIdx.x) * 4;
#pragma unroll
    for (int i = 0; i < 4; i++) {
        const int idx  = base + i;
        const int head = idx >> 16;
        const int rem  = idx & 65535;
        const int f = rem >> 7, o = rem & 127;
        const int b = f >> 7, f0 = f & 127;
        const int ob = o >> 5, oc = o & 31;
        const float s = ((0x5390u >> ((b << 2) | ob)) & 1u) ? -1.0f : 1.0f;
        ham[idx] = s * W[(head << 14) + (f0 << 7) + (((b ^ ob) << 5) | oc)];
    }
}

// ---------------------------------------------------------------------------
// K1: h[head][n][o] = sum_f x[n][f] * ham[head][f][o]   (fp32 out, 8 MB)
// block: 32 rows x 128 cols, thread tile 2x8, K-chunks of 32 staged in LDS.
// ham read straight from global (16 KB/chunk, L1/L2 resident).
// ---------------------------------------------------------------------------
__global__ __launch_bounds__(256) void k_h(const float* __restrict__ x,
                                           const float* __restrict__ ham,
                                           float* __restrict__ hG) {
    __shared__ float xs[32][36];   // [k][row], +4 pad keeps float2 reads aligned
    const int t = threadIdx.x;
    const int head = blockIdx.y;
    const int n0 = blockIdx.x * 32;
    const int rowg = t >> 4;        // 0..15 -> rows rowg*2..+1
    const int colg = t & 15;        // cols colg*8..+7
    float acc[2][8];
#pragma unroll
    for (int r = 0; r < 2; r++)
#pragma unroll
        for (int c = 0; c < 8; c++) acc[r][c] = 0.0f;
    const float* hamh = ham + ((size_t)head << 16);      // 512*128
    const int sr  = t >> 3;         // 0..31 staging row
    const int skq = (t & 7) << 2;   // 0..28 staging k-quad
    for (int kc = 0; kc < 16; kc++) {
        const float* xp = x + (size_t)(n0 + sr) * 512 + kc * 32 + skq;
        const float4 u = *(const float4*)xp;             // 16B aligned
        xs[skq + 0][sr] = u.x;
        xs[skq + 1][sr] = u.y;
        xs[skq + 2][sr] = u.z;
        xs[skq + 3][sr] = u.w;
        __syncthreads();
        const float* hp = hamh + (size_t)kc * 32 * 128 + colg * 8;
#pragma unroll 4
        for (int kk = 0; kk < 32; kk++) {
            const float2 xv = *(const float2*)&xs[kk][rowg * 2];
            const float4 h0 = *(const float4*)(hp + kk * 128);
            const float4 h1 = *(const float4*)(hp + kk * 128 + 4);
            const float hc[8] = {h0.x, h0.y, h0.z, h0.w, h1.x, h1.y, h1.z, h1.w};
#pragma unroll
            for (int c = 0; c < 8; c++) {
                acc[0][c] += xv.x * hc[c];
                acc[1][c] += xv.y * hc[c];
            }
        }
        __syncthreads();
    }
#pragma unroll
    for (int r = 0; r < 2; r++) {
        const int n = n0 + rowg * 2 + r;
        float* op = hG + (((size_t)head << 12) + n) * 128 + colg * 8;
        const float4 o0 = {acc[r][0], acc[r][1], acc[r][2], acc[r][3]};
        const float4 o1 = {acc[r][4], acc[r][5], acc[r][6], acc[r][7]};
        *(float4*)op = o0;
        *(float4*)(op + 4) = o1;
    }
}

// ---------------------------------------------------------------------------
// K2: f_src/f_dst per (head,n): one wave per row, shuffle reduce over 128 cols.
// ---------------------------------------------------------------------------
__global__ __launch_bounds__(256) void k_f(const float* __restrict__ hG,
                                           const float* __restrict__ a,
                                           float* __restrict__ fs,
                                           float* __restrict__ fd) {
    const int gid  = blockIdx.x * 256 + threadIdx.x;
    const int w    = gid >> 6;        // (head,n) id, 0..16383
    const int lane = gid & 63;
    const int head = w >> 12;
    const float* hp = hG + (size_t)w * 128;
    const float v0 = hp[lane], v1 = hp[64 + lane];
    const float* ap = a + (head << 8);
    float s = v0 * ap[lane]       + v1 * ap[64 + lane];
    float d = v0 * ap[128 + lane] + v1 * ap[192 + lane];
#pragma unroll
    for (int off = 32; off > 0; off >>= 1) {
        s += __shfl_xor(s, off, 64);
        d += __shfl_xor(d, off, 64);
    }
    if (lane == 0) { fs[w] = s; fd[w] = d; }
}

// ---------------------------------------------------------------------------
// K3: per (n): rowmax M[h] and softmax denom L[h] over all m, all 4 heads.
// e = adj>0 ? leaky(fs[n]+fd[m]) : NEGINF.  Stores M and 1/L.
// All-masked rows fall out naturally: M=NEGINF, e-M=0, L=4096 (uniform attn).
// ---------------------------------------------------------------------------
__global__ __launch_bounds__(256) void k_ml(const int* __restrict__ adj,
                                            const float* __restrict__ fs,
                                            const float* __restrict__ fd,
                                            float* __restrict__ Mo,
                                            float* __restrict__ iLo) {
    const int n = blockIdx.x;
    const int t = threadIdx.x;
    __shared__ float sm[4][4];
    float fsn[4];
#pragma unroll
    for (int h = 0; h < 4; h++) fsn[h] = fs[(h << 12) + n];
    const int* arow = adj + (size_t)n * 4096;
    float mx[4] = {NEGINF, NEGINF, NEGINF, NEGINF};
    for (int m = t; m < 4096; m += 256) {
        const int av = arow[m];
#pragma unroll
        for (int h = 0; h < 4; h++) {
            const float z = fsn[h] + fd[(h << 12) + m];
            float e = fmaxf(z, ALPHA * z);
            e = av > 0 ? e : NEGINF;
            mx[h] = fmaxf(mx[h], e);
        }
    }
#pragma unroll
    for (int h = 0; h < 4; h++)
#pragma unroll
        for (int off = 32; off > 0; off >>= 1)
            mx[h] = fmaxf(mx[h], __shfl_xor(mx[h], off, 64));
    const int wv = t >> 6, lane = t & 63;
    if (lane == 0)
        for (int h = 0; h < 4; h++) sm[wv][h] = mx[h];
    __syncthreads();
    float Mh[4];
#pragma unroll
    for (int h = 0; h < 4; h++)
        Mh[h] = fmaxf(fmaxf(sm[0][h], sm[1][h]), fmaxf(sm[2][h], sm[3][h]));
    __syncthreads();
    float sum[4] = {0.f, 0.f, 0.f, 0.f};
    for (int m = t; m < 4096; m += 256) {
        const int av = arow[m];
#pragma unroll
        for (int h = 0; h < 4; h++) {
            const float z = fsn[h] + fd[(h << 12) + m];
            float e = fmaxf(z, ALPHA * z);
            e = av > 0 ? e : NEGINF;
            sum[h] += __expf(e - Mh[h]);
        }
    }
#pragma unroll
    for (int h = 0; h < 4; h++)
#pragma unroll
        for (int off = 32; off > 0; off >>= 1)
            sum[h] += __shfl_xor(sum[h], off, 64);
    if (lane == 0)
        for (int h = 0; h < 4; h++) sm[wv][h] = sum[h];
    __syncthreads();
    if (t == 0) {
        for (int h = 0; h < 4; h++) {
            const float L = sm[0][h] + sm[1][h] + sm[2][h] + sm[3][h];
            Mo[(h << 12) + n]  = Mh[h];
            iLo[(h << 12) + n] = 1.0f / L;
        }
    }
}

// ---------------------------------------------------------------------------
// K4: h_prime[head][n][:] = sum_m attn(n,m) * h[head][m][:], fused ELU, fp32 out.
// block: (head, 32-row tile) x all m in chunks of 32. Weights recomputed into
// LDS tile per chunk; h rows read from global (L1/L2 resident) to keep the
// LDS pipe for weights only. Thread tile 2 rows x 8 cols (fp32 acc).
// ---------------------------------------------------------------------------
__global__ __launch_bounds__(256) void k_attn(const int* __restrict__ adj,
                                              const float* __restrict__ fs,
                                              const float* __restrict__ fd,
                                              const float* __restrict__ Mg,
                                              const float* __restrict__ iLg,
                                              const float* __restrict__ hG,
                                              float* __restrict__ out) {
    __shared__ float wsm[32][36];   // [m][row] (+4 pad)
    __shared__ float fs_s[32], M_s[32], iL_s[32];
    const int t = threadIdx.x;
    const int head = blockIdx.y;
    const int n0 = blockIdx.x * 32;
    if (t < 32) {
        fs_s[t] = fs[(head << 12) + n0 + t];
        M_s[t]  = Mg[(head << 12) + n0 + t];
        iL_s[t] = iLg[(head << 12) + n0 + t];
    }
    __syncthreads();
    const int rowg = t >> 4, colg = t & 15;
    const int mw = t & 31, rbase = (t >> 5) << 2;   // weight tile: 4 rows per thread
    float acc[2][8];
#pragma unroll
    for (int r = 0; r < 2; r++)
#pragma unroll
        for (int c = 0; c < 8; c++) acc[r][c] = 0.0f;
    const float* hbase = hG + (((size_t)head << 12) << 7);
    const float* fdh = fd + (head << 12);
    for (int mc = 0; mc < 128; mc++) {
        const int m = mc * 32 + mw;
        const float fdv = fdh[m];
#pragma unroll
        for (int rr = 0; rr < 4; rr++) {
            const int r = rbase + rr;
            const int av = adj[(size_t)(n0 + r) * 4096 + m];
            const float z = fs_s[r] + fdv;
            float e = fmaxf(z, ALPHA * z);
            e = av > 0 ? e : NEGINF;
            wsm[mw][r] = __expf(e - M_s[r]) * iL_s[r];
        }
        __syncthreads();
        const float* hp = hbase + (size_t)(mc * 32) * 128 + colg * 8;
#pragma unroll 4
        for (int mm = 0; mm < 32; mm++) {
            const float2 wv = *(const float2*)&wsm[mm][rowg * 2];
            const float4 h0 = *(const float4*)(hp + mm * 128);
            const float4 h1 = *(const float4*)(hp + mm * 128 + 4);
            const float hc[8] = {h0.x, h0.y, h0.z, h0.w, h1.x, h1.y, h1.z, h1.w};
#pragma unroll
            for (int c = 0; c < 8; c++) {
                acc[0][c] += wv.x * hc[c];
                acc[1][c] += wv.y * hc[c];
            }
        }
        __syncthreads();
    }
#pragma unroll
    for (int r = 0; r < 2; r++) {
        const int n = n0 + rowg * 2 + r;
        float* op = out + (size_t)n * 512 + (head << 7) + colg * 8;
        float v[8];
#pragma unroll
        for (int c = 0; c < 8; c++) {
            const float u = acc[r][c];
            v[c] = u > 0.0f ? u : expm1f(u);    // ELU(alpha=1)
        }
        const float4 o0 = {v[0], v[1], v[2], v[3]};
        const float4 o1 = {v[4], v[5], v[6], v[7]};
        *(float4*)op = o0;
        *(float4*)(op + 4) = o1;
    }
}

extern "C" void kernel_launch(void* const* d_in, const int* in_sizes, int n_in,
                              void* d_out, int out_size, void* d_ws, size_t ws_size,
                              hipStream_t stream) {
    (void)in_sizes; (void)n_in; (void)out_size; (void)ws_size;
    const float* x   = (const float*)d_in[0];   // (4096,512) fp32
    const int*   adj = (const int*)d_in[1];     // (4096,4096) i32
    const float* W   = (const float*)d_in[2];   // (4,128,128) fp32
    const float* a   = (const float*)d_in[3];   // (4,256) fp32
    float* out = (float*)d_out;                 // (4096,512) fp32

    char* ws = (char*)d_ws;
    float* hG  = (float*)(ws);                              // 8 MB  (H,N,128) fp32
    float* ham = (float*)(ws + (8u << 20));                 // 1 MB  (H,512,128) fp32
    float* fs  = (float*)(ws + (9u << 20));                 // 64 KB (H,N)
    float* fd  = (float*)(ws + (9u << 20) + (64u << 10));   // 64 KB
    float* Mg  = (float*)(ws + (9u << 20) + (128u << 10));  // 64 KB
    float* iLg = (float*)(ws + (9u << 20) + (192u << 10));  // 64 KB

    hipLaunchKernelGGL(k_ham,  dim3(256),      dim3(256), 0, stream, W, ham);
    hipLaunchKernelGGL(k_h,    dim3(128, 4),   dim3(256), 0, stream, x, ham, hG);
    hipLaunchKernelGGL(k_f,    dim3(4096),     dim3(256), 0, stream, hG, a, fs, fd);
    hipLaunchKernelGGL(k_ml,   dim3(4096),     dim3(256), 0, stream, adj, fs, fd, Mg, iLg);
    hipLaunchKernelGGL(k_attn, dim3(128, 4),   dim3(256), 0, stream, adj, fs, fd, Mg, iLg, hG, out);
}

// Round 3
// 301.759 us; speedup vs baseline: 2.4146x; 2.4146x over previous
//
#include <hip/hip_runtime.h>
#include <math.h>

#define ALPHA  0.2f
#define NEGINF -9000000000000000.0f

typedef __attribute__((ext_vector_type(8))) short short8;
typedef __attribute__((ext_vector_type(4))) float f32x4;

__device__ __forceinline__ unsigned short f2bf(float f) {
    union { float f; unsigned int i; } v; v.f = f;
    unsigned int x = v.i;
    x += 0x7fffu + ((x >> 16) & 1u);   // round-to-nearest-even
    return (unsigned short)(x >> 16);
}

// ---------------------------------------------------------------------------
// K0: hamilton (H,512,128) fp32 from W (H,128,128) fp32.
// ham[h][b*128+f0][ob*32+oc] = s(b,ob)*W[h][f0][(b^ob)*32+oc], sign mask 0x5390
// ---------------------------------------------------------------------------
__global__ __launch_bounds__(256) void k_ham(const float* __restrict__ W,
                                             float* __restrict__ ham) {
    const int base = (blockIdx.x * 256 + threadIdx.x) * 4;
#pragma unroll
    for (int i = 0; i < 4; i++) {
        const int idx  = base + i;
        const int head = idx >> 16;
        const int rem  = idx & 65535;
        const int f = rem >> 7, o = rem & 127;
        const int b = f >> 7, f0 = f & 127;
        const int ob = o >> 5, oc = o & 31;
        const float s = ((0x5390u >> ((b << 2) | ob)) & 1u) ? -1.0f : 1.0f;
        ham[idx] = s * W[(head << 14) + (f0 << 7) + (((b ^ ob) << 5) | oc)];
    }
}

// ---------------------------------------------------------------------------
// K1: pack adj (4096x4096 i32) -> bitmask, 2 MB. ballot bit l = lane l = m.
// ---------------------------------------------------------------------------
__global__ __launch_bounds__(256) void k_pack(const int* __restrict__ adj,
                                              unsigned long long* __restrict__ adjp64) {
    const int wid  = (blockIdx.x * 256 + threadIdx.x) >> 6;
    const int lane = threadIdx.x & 63;
    const int nw   = (gridDim.x * 256) >> 6;
    for (int i = wid; i < 262144; i += nw) {
        const int v = adj[(size_t)i * 64 + lane];
        const unsigned long long mask = __ballot(v > 0);
        if (lane == 0) adjp64[i] = mask;
    }
}

// ---------------------------------------------------------------------------
// K2: h = x @ ham (per head). Writes hBT[head][col][m] (bf16, transposed, for
// MFMA B-frags) and computes f_src/f_dst in-register (fp32 exact) via wave
// shuffle reduction (each wave owns 8 rows; lanes = 64 col-pairs).
// ---------------------------------------------------------------------------
__global__ __launch_bounds__(256) void k_h(const float* __restrict__ x,
                                           const float* __restrict__ ham,
                                           const float* __restrict__ a,
                                           unsigned short* __restrict__ hBT,
                                           float* __restrict__ fs,
                                           float* __restrict__ fd) {
    __shared__ float xs[32][36];   // [k][row], stride 144B (16B-aligned rows-of-8)
    const int t = threadIdx.x;
    const int head = blockIdx.y;
    const int n0 = blockIdx.x * 32;
    const int rowg = t >> 6;        // wave id: rows rowg*8..+7 (wave-uniform)
    const int colg = t & 63;        // cols colg*2, colg*2+1
    float acc[8][2];
#pragma unroll
    for (int r = 0; r < 8; r++) { acc[r][0] = 0.0f; acc[r][1] = 0.0f; }
    const float* hamh = ham + ((size_t)head << 16);
    const int sr  = t >> 3;         // staging row 0..31
    const int skq = (t & 7) << 2;   // staging k-quad
    for (int kc = 0; kc < 16; kc++) {
        const float4 u = *(const float4*)(x + (size_t)(n0 + sr) * 512 + kc * 32 + skq);
        xs[skq + 0][sr] = u.x;
        xs[skq + 1][sr] = u.y;
        xs[skq + 2][sr] = u.z;
        xs[skq + 3][sr] = u.w;
        __syncthreads();
        const float* hp = hamh + (size_t)kc * 32 * 128 + colg * 2;
#pragma unroll 8
        for (int kk = 0; kk < 32; kk++) {
            const float4 x0 = *(const float4*)&xs[kk][rowg * 8];      // broadcast
            const float4 x1 = *(const float4*)&xs[kk][rowg * 8 + 4];
            const float2 hv = *(const float2*)(hp + kk * 128);
            const float xr[8] = {x0.x, x0.y, x0.z, x0.w, x1.x, x1.y, x1.z, x1.w};
#pragma unroll
            for (int r = 0; r < 8; r++) {
                acc[r][0] += xr[r] * hv.x;
                acc[r][1] += xr[r] * hv.y;
            }
        }
        __syncthreads();
    }
    // hBT write: col-major bf16, 16B contiguous per col
#pragma unroll
    for (int c = 0; c < 2; c++) {
        const int col = colg * 2 + c;
        unsigned int pk[4];
#pragma unroll
        for (int p = 0; p < 4; p++)
            pk[p] = (unsigned int)f2bf(acc[2 * p][c]) | ((unsigned int)f2bf(acc[2 * p + 1][c]) << 16);
        const uint4 o = {pk[0], pk[1], pk[2], pk[3]};
        *(uint4*)(hBT + ((size_t)(head * 128 + col) * 4096 + n0 + rowg * 8)) = o;
    }
    // f_src/f_dst: per-row dot with a, reduced across the wave's 64 col-pairs
    const float as0 = a[(head << 8) + colg * 2],       as1 = a[(head << 8) + colg * 2 + 1];
    const float ad0 = a[(head << 8) + 128 + colg * 2], ad1 = a[(head << 8) + 128 + colg * 2 + 1];
    float fsr[8], fdr[8];
#pragma unroll
    for (int r = 0; r < 8; r++) {
        fsr[r] = acc[r][0] * as0 + acc[r][1] * as1;
        fdr[r] = acc[r][0] * ad0 + acc[r][1] * ad1;
    }
#pragma unroll
    for (int off = 32; off > 0; off >>= 1)
#pragma unroll
        for (int r = 0; r < 8; r++) {
            fsr[r] += __shfl_xor(fsr[r], off, 64);
            fdr[r] += __shfl_xor(fdr[r], off, 64);
        }
    if ((t & 63) == 0) {
#pragma unroll
        for (int r = 0; r < 8; r++) {
            fs[(head << 12) + n0 + rowg * 8 + r] = fsr[r];
            fd[(head << 12) + n0 + rowg * 8 + r] = fdr[r];
        }
    }
}

// ---------------------------------------------------------------------------
// K3: fdmax[h] = max_m fd[h][m]  (valid softmax upper bound via monotone leaky)
// ---------------------------------------------------------------------------
__global__ __launch_bounds__(256) void k_fdmax(const float* __restrict__ fd,
                                               float* __restrict__ fdmax) {
    const int h = blockIdx.x, t = threadIdx.x;
    __shared__ float sm[4];
    float mx = NEGINF;
    for (int i = t; i < 4096; i += 256) mx = fmaxf(mx, fd[(h << 12) + i]);
#pragma unroll
    for (int off = 32; off > 0; off >>= 1) mx = fmaxf(mx, __shfl_xor(mx, off, 64));
    if ((t & 63) == 0) sm[t >> 6] = mx;
    __syncthreads();
    if (t == 0) fdmax[h] = fmaxf(fmaxf(sm[0], sm[1]), fmaxf(sm[2], sm[3]));
}

// ---------------------------------------------------------------------------
// K4: sum-only softmax pass. M[h][n] = leaky(fs[n]+fdmax[h]) >= row max.
// L = sum over unmasked exp(e - M). L==0 (all-masked) -> M=NEGINF, iL=1/4096.
// ---------------------------------------------------------------------------
__global__ __launch_bounds__(256) void k_ml(const unsigned char* __restrict__ adjp,
                                            const float* __restrict__ fs,
                                            const float* __restrict__ fd,
                                            const float* __restrict__ fdmax,
                                            float* __restrict__ Mo,
                                            float* __restrict__ iLo) {
    const int n = blockIdx.x, t = threadIdx.x;
    __shared__ float sm[4][4];
    float fsn[4], Mh[4];
#pragma unroll
    for (int h = 0; h < 4; h++) {
        fsn[h] = fs[(h << 12) + n];
        const float z = fsn[h] + fdmax[h];
        Mh[h] = fmaxf(z, ALPHA * z);
    }
    float sum[4] = {0.f, 0.f, 0.f, 0.f};
    const unsigned char* aprow = adjp + (size_t)n * 512;
    for (int g = t; g < 512; g += 256) {
        const unsigned int byte = aprow[g];
#pragma unroll
        for (int h = 0; h < 4; h++) {
            const float* fh = fd + (h << 12) + g * 8;
            const float4 f0 = *(const float4*)fh;
            const float4 f1 = *(const float4*)(fh + 4);
            const float fv[8] = {f0.x, f0.y, f0.z, f0.w, f1.x, f1.y, f1.z, f1.w};
#pragma unroll
            for (int j = 0; j < 8; j++) {
                const float z = fsn[h] + fv[j];
                const float e = fmaxf(z, ALPHA * z);
                const float w = __expf(e - Mh[h]);
                sum[h] += ((byte >> j) & 1u) ? w : 0.0f;
            }
        }
    }
#pragma unroll
    for (int h = 0; h < 4; h++)
#pragma unroll
        for (int off = 32; off > 0; off >>= 1)
            sum[h] += __shfl_xor(sum[h], off, 64);
    if ((t & 63) == 0)
        for (int h = 0; h < 4; h++) sm[t >> 6][h] = sum[h];
    __syncthreads();
    if (t == 0) {
#pragma unroll
        for (int h = 0; h < 4; h++) {
            const float L = sm[0][h] + sm[1][h] + sm[2][h] + sm[3][h];
            if (L > 0.0f) { Mo[(h << 12) + n] = Mh[h];  iLo[(h << 12) + n] = 1.0f / L; }
            else          { Mo[(h << 12) + n] = NEGINF; iLo[(h << 12) + n] = 1.0f / 4096.0f; }
        }
    }
}

// ---------------------------------------------------------------------------
// K5: h_prime = attn @ h via bf16 MFMA 16x16x32, fused ELU.
// Block: (32 rows, head). 4 waves x 32 cols. Weight tile (32n x 32m) bf16 in
// LDS (stride 40 halfs); B-frags straight from hBT (16B/lane, L2-resident),
// next-chunk B prefetched. Verified layouts: A[m=lane&15][k=quad*8+j],
// B[col=lane&15][k=quad*8+j], C/D row=quad*4+reg, col=lane&15.
// ---------------------------------------------------------------------------
__global__ __launch_bounds__(256) void k_attn(const unsigned char* __restrict__ adjp,
                                              const float* __restrict__ fs,
                                              const float* __restrict__ fd,
                                              const float* __restrict__ Mg,
                                              const float* __restrict__ iLg,
                                              const unsigned short* __restrict__ hBT,
                                              float* __restrict__ out) {
    __shared__ unsigned short wl[32 * 40];   // [n][m], row stride 40 halfs (80B)
    const int t = threadIdx.x;
    const int head = blockIdx.y;
    const int n0 = blockIdx.x * 32;
    const int wv = t >> 6, lane = t & 63;
    const int quad = lane >> 4, nl = lane & 15;
    // weight-compute role: thread -> (row tn, m-quad q)
    const int tn = t & 31, q = t >> 5;
    const float fs_v = fs[(head << 12) + n0 + tn];
    const float M_v  = Mg[(head << 12) + n0 + tn];
    const float iL_v = iLg[(head << 12) + n0 + tn];
    const unsigned char* aprow = adjp + (size_t)(n0 + tn) * 512;
    const float* fdh = fd + (head << 12);
    // mfma role
    const unsigned short* bptr = hBT + ((size_t)(head * 128 + wv * 32 + nl) * 4096) + quad * 8;
    f32x4 acc[2][2];
#pragma unroll
    for (int rt = 0; rt < 2; rt++)
#pragma unroll
        for (int ct = 0; ct < 2; ct++) acc[rt][ct] = (f32x4){0.f, 0.f, 0.f, 0.f};
    short8 bcur[2], bnxt[2];
#pragma unroll
    for (int ct = 0; ct < 2; ct++) bcur[ct] = *(const short8*)(bptr + ct * 65536);
    for (int mc = 0; mc < 128; mc++) {
        const int m0 = mc * 32;
        // --- cooperative weight tile (bf16) ---
        const unsigned int byte = aprow[(m0 >> 3) + (q >> 1)];
        const unsigned int bits = (byte >> ((q & 1) * 4)) & 0xFu;
        const float4 fdv = *(const float4*)(fdh + m0 + q * 4);
        const float fvv[4] = {fdv.x, fdv.y, fdv.z, fdv.w};
        unsigned int pk[2];
#pragma unroll
        for (int pp = 0; pp < 2; pp++) {
            unsigned short lo, hi;
#pragma unroll
            for (int s = 0; s < 2; s++) {
                const int j = pp * 2 + s;
                const float z = fs_v + fvv[j];
                float e = fmaxf(z, ALPHA * z);
                e = ((bits >> j) & 1u) ? e : NEGINF;
                const float w = __expf(e - M_v) * iL_v;
                const unsigned short b = f2bf(w);
                if (s == 0) lo = b; else hi = b;
            }
            pk[pp] = (unsigned int)lo | ((unsigned int)hi << 16);
        }
        *(uint2*)&wl[tn * 40 + q * 4] = *(uint2*)pk;
        __syncthreads();
        short8 afrag[2];
#pragma unroll
        for (int rt = 0; rt < 2; rt++)
            afrag[rt] = *(const short8*)&wl[(rt * 16 + nl) * 40 + quad * 8];
        // prefetch next chunk's B
        const int m0n = (mc < 127) ? (m0 + 32) : 0;
#pragma unroll
        for (int ct = 0; ct < 2; ct++) bnxt[ct] = *(const short8*)(bptr + ct * 65536 + m0n);
#pragma unroll
        for (int rt = 0; rt < 2; rt++)
#pragma unroll
            for (int ct = 0; ct < 2; ct++)
                acc[rt][ct] = __builtin_amdgcn_mfma_f32_16x16x32_bf16(
                    afrag[rt], bcur[ct], acc[rt][ct], 0, 0, 0);
        __syncthreads();
        bcur[0] = bnxt[0]; bcur[1] = bnxt[1];
    }
#pragma unroll
    for (int rt = 0; rt < 2; rt++)
#pragma unroll
        for (int ct = 0; ct < 2; ct++)
#pragma unroll
            for (int r = 0; r < 4; r++) {
                const int row = rt * 16 + quad * 4 + r;
                const int col = head * 128 + wv * 32 + ct * 16 + nl;
                float v = acc[rt][ct][r];
                v = v > 0.0f ? v : expm1f(v);   // ELU
                out[(size_t)(n0 + row) * 512 + col] = v;
            }
}

extern "C" void kernel_launch(void* const* d_in, const int* in_sizes, int n_in,
                              void* d_out, int out_size, void* d_ws, size_t ws_size,
                              hipStream_t stream) {
    (void)in_sizes; (void)n_in; (void)out_size; (void)ws_size;
    const float* x   = (const float*)d_in[0];   // (4096,512) fp32
    const int*   adj = (const int*)d_in[1];     // (4096,4096) i32
    const float* W   = (const float*)d_in[2];   // (4,128,128) fp32
    const float* a   = (const float*)d_in[3];   // (4,256) fp32
    float* out = (float*)d_out;                 // (4096,512) fp32

    char* ws = (char*)d_ws;
    float*          ham   = (float*)(ws);                       // 1 MB
    unsigned short* hBT   = (unsigned short*)(ws + (1u << 20)); // 4 MB (H,128,4096) bf16
    unsigned char*  adjp  = (unsigned char*)(ws + (5u << 20));  // 2 MB bitmask
    float*          fs    = (float*)(ws + (7u << 20));                      // 64 KB
    float*          fd    = (float*)(ws + (7u << 20) + (64u << 10));        // 64 KB
    float*          Mg    = (float*)(ws + (7u << 20) + (128u << 10));       // 64 KB
    float*          iLg   = (float*)(ws + (7u << 20) + (192u << 10));       // 64 KB
    float*          fdmax = (float*)(ws + (7u << 20) + (256u << 10));       // 16 B

    hipLaunchKernelGGL(k_ham,   dim3(256),     dim3(256), 0, stream, W, ham);
    hipLaunchKernelGGL(k_pack,  dim3(512),     dim3(256), 0, stream, adj, (unsigned long long*)adjp);
    hipLaunchKernelGGL(k_h,     dim3(128, 4),  dim3(256), 0, stream, x, ham, a, hBT, fs, fd);
    hipLaunchKernelGGL(k_fdmax, dim3(4),       dim3(256), 0, stream, fd, fdmax);
    hipLaunchKernelGGL(k_ml,    dim3(4096),    dim3(256), 0, stream, adjp, fs, fd, fdmax, Mg, iLg);
    hipLaunchKernelGGL(k_attn,  dim3(128, 4),  dim3(256), 0, stream, adjp, fs, fd, Mg, iLg, hBT, out);
}

// Round 4
// 266.305 us; speedup vs baseline: 2.7361x; 1.1331x over previous
//
#include <hip/hip_runtime.h>
#include <math.h>

#define ALPHA 0.2f

typedef __attribute__((ext_vector_type(8))) short short8;
typedef __attribute__((ext_vector_type(4))) float f32x4;

union U8 { short8 s; uint4 u; };

__device__ __forceinline__ unsigned short f2bf(float f) {
    union { float f; unsigned int i; } v; v.f = f;
    unsigned int x = v.i;
    x += 0x7fffu + ((x >> 16) & 1u);   // RNE
    return (unsigned short)(x >> 16);
}
__device__ __forceinline__ unsigned int pack_rne(float lo, float hi) {
    return (unsigned int)f2bf(lo) | ((unsigned int)f2bf(hi) << 16);
}
// truncating bf16 pack (bias cancels in w/L since L sums the same truncated w)
__device__ __forceinline__ unsigned int pack_trunc(float lo, float hi) {
#if __has_builtin(__builtin_amdgcn_perm)
    return __builtin_amdgcn_perm(__float_as_uint(hi), __float_as_uint(lo), 0x07060302u);
#else
    return (__float_as_uint(lo) >> 16) | (__float_as_uint(hi) & 0xFFFF0000u);
#endif
}
// bit j of x -> 0x0 / 0xFFFFFFFF
__device__ __forceinline__ unsigned int bitmask1(unsigned int x, int j) {
#if __has_builtin(__builtin_amdgcn_sbfe)
    return (unsigned int)__builtin_amdgcn_sbfe((int)x, j, 1);
#else
    return (unsigned int)(((int)(x << (31 - j))) >> 31);
#endif
}

// ---------------------------------------------------------------------------
// K0: x fp32 -> xbf bf16 (RNE). 2M elems, 8 per thread.
// ---------------------------------------------------------------------------
__global__ __launch_bounds__(256) void k_xcvt(const float* __restrict__ x,
                                              unsigned short* __restrict__ xbf) {
    const int gid = blockIdx.x * 256 + threadIdx.x;       // 262144
    const float4* xp = (const float4*)x + (size_t)gid * 2;
    const float4 f0 = xp[0], f1 = xp[1];
    const uint4 o = {pack_rne(f0.x, f0.y), pack_rne(f0.z, f0.w),
                     pack_rne(f1.x, f1.y), pack_rne(f1.z, f1.w)};
    ((uint4*)xbf)[gid] = o;
}

// ---------------------------------------------------------------------------
// K1: hamilton, transposed + bf16: hamT[head][o(128)][f(512)].
// ham[h][b*128+f0][ob*32+oc] = s(b,ob)*W[h][f0][(b^ob)*32+oc], sign mask 0x5390
// ---------------------------------------------------------------------------
__global__ __launch_bounds__(256) void k_ham(const float* __restrict__ W,
                                             unsigned short* __restrict__ hamT) {
    const int gid = blockIdx.x * 256 + threadIdx.x;       // 32768
    const int head = gid >> 13;
    const int rem  = gid & 8191;
    const int o = rem >> 6, f8 = rem & 63;
    const int ob = o >> 5, oc = o & 31;
    float v[8];
#pragma unroll
    for (int j = 0; j < 8; j++) {
        const int f = f8 * 8 + j;
        const int b = f >> 7, f0 = f & 127;
        const float s = ((0x5390u >> ((b << 2) | ob)) & 1u) ? -1.0f : 1.0f;
        v[j] = s * W[(head << 14) + (f0 << 7) + (((b ^ ob) << 5) | oc)];
    }
    const uint4 pk = {pack_rne(v[0], v[1]), pack_rne(v[2], v[3]),
                      pack_rne(v[4], v[5]), pack_rne(v[6], v[7])};
    *(uint4*)(hamT + (size_t)(head * 128 + o) * 512 + f8 * 8) = pk;
}

// ---------------------------------------------------------------------------
// K2: pack adj -> bitmask (2 MB). bit l of word i = (adj[i*64+l] > 0).
// ---------------------------------------------------------------------------
__global__ __launch_bounds__(256) void k_pack(const int* __restrict__ adj,
                                              unsigned long long* __restrict__ adjp64) {
    const int wid  = (blockIdx.x * 256 + threadIdx.x) >> 6;
    const int lane = threadIdx.x & 63;
    const int nw   = (gridDim.x * 256) >> 6;
    for (int i = wid; i < 262144; i += nw) {
        const int v = adj[(size_t)i * 64 + lane];
        const unsigned long long mask = __ballot(v > 0);
        if (lane == 0) adjp64[i] = mask;
    }
}

// ---------------------------------------------------------------------------
// K3: h = x @ ham via bf16 MFMA. Block: 4 waves x 16 rows, 128 cols, K=512.
// Outputs: hBT[head][col][n] bf16 (B-layout for k_attn), and per-row
// softmax factors fsE=(exp(fs),exp(a*fs)), fdE=(exp(fd),exp(a*fd)) fp32
// computed from the fp32 accumulators.
// ---------------------------------------------------------------------------
__global__ __launch_bounds__(256) void k_h(const unsigned short* __restrict__ xbf,
                                           const unsigned short* __restrict__ hamT,
                                           const float* __restrict__ a,
                                           unsigned short* __restrict__ hBT,
                                           float2* __restrict__ fsE,
                                           float2* __restrict__ fdE) {
    const int t = threadIdx.x;
    const int head = blockIdx.y;
    const int n0 = blockIdx.x * 64;
    const int wv = t >> 6, lane = t & 63;
    const int quad = lane >> 4, nl = lane & 15;
    const unsigned short* ap = xbf + (size_t)(n0 + wv * 16 + nl) * 512 + quad * 8;
    const unsigned short* bp = hamT + (size_t)(head * 128 + nl) * 512 + quad * 8;
    f32x4 acc[8];
#pragma unroll
    for (int ct = 0; ct < 8; ct++) acc[ct] = (f32x4){0.f, 0.f, 0.f, 0.f};
    for (int kc = 0; kc < 16; kc++) {
        const short8 af = *(const short8*)(ap + kc * 32);
#pragma unroll
        for (int ct = 0; ct < 8; ct++) {
            const short8 bf_ = *(const short8*)(bp + (size_t)ct * 16 * 512 + kc * 32);
            acc[ct] = __builtin_amdgcn_mfma_f32_16x16x32_bf16(af, bf_, acc[ct], 0, 0, 0);
        }
    }
    // hBT: lane covers col=ct*16+nl, rows n0+wv*16+quad*4 .. +3
    const int rbase = n0 + wv * 16 + quad * 4;
#pragma unroll
    for (int ct = 0; ct < 8; ct++) {
        const uint2 pk = {pack_rne(acc[ct][0], acc[ct][1]), pack_rne(acc[ct][2], acc[ct][3])};
        *(uint2*)(hBT + (size_t)(head * 128 + ct * 16 + nl) * 4096 + rbase) = pk;
    }
    // f_src/f_dst from fp32 accs: reduce over cols (8 ct in-thread, 16 nl by shuffle)
    float fsr[4] = {0.f, 0.f, 0.f, 0.f}, fdr[4] = {0.f, 0.f, 0.f, 0.f};
#pragma unroll
    for (int ct = 0; ct < 8; ct++) {
        const int col = ct * 16 + nl;
        const float as = a[head * 256 + col];
        const float ad = a[head * 256 + 128 + col];
#pragma unroll
        for (int r = 0; r < 4; r++) {
            fsr[r] += acc[ct][r] * as;
            fdr[r] += acc[ct][r] * ad;
        }
    }
#pragma unroll
    for (int off = 1; off < 16; off <<= 1)
#pragma unroll
        for (int r = 0; r < 4; r++) {
            fsr[r] += __shfl_xor(fsr[r], off, 64);
            fdr[r] += __shfl_xor(fdr[r], off, 64);
        }
    if (nl == 0) {
#pragma unroll
        for (int r = 0; r < 4; r++) {
            const int n = rbase + r;
            fsE[(head << 12) + n] = make_float2(__expf(fsr[r]), __expf(ALPHA * fsr[r]));
            fdE[(head << 12) + n] = make_float2(__expf(fdr[r]), __expf(ALPHA * fdr[r]));
        }
    }
}

// ---------------------------------------------------------------------------
// K4: h' = softmax(mask(leaky(fs+fd))) @ h, fused ELU.
// exp(leaky(z)) == max(exp(fs)exp(fd), exp(a*fs)exp(a*fd))  [monotone exp, a>0]
// Weights built per-wave directly in MFMA A-frag layout (registers, no LDS,
// no K-loop barriers). L (softmax denom) accumulated by a ones-B MFMA and
// divided out in the epilogue — no transcendentals in the N^2 path.
// Block: 4 waves, same 32 rows x 128 cols, m-split x4; combine via LDS once.
// ---------------------------------------------------------------------------
__global__ __launch_bounds__(256, 2) void k_attn(const unsigned char* __restrict__ adjp,
                                                 const float2* __restrict__ fsE,
                                                 const float2* __restrict__ fdE,
                                                 const unsigned short* __restrict__ hBT,
                                                 float* __restrict__ out) {
    __shared__ f32x4 cbuf[3584];   // 16k*3 partials + 2*4 L slots, 56 KB
    const int t = threadIdx.x;
    const int head = blockIdx.y;
    const int n0 = blockIdx.x * 32;
    const int wv = t >> 6, lane = t & 63;
    const int quad = lane >> 4, nl = lane & 15;
    const int m0base = wv << 10;                 // wave's m-quarter
    // per-row constants (A rows = nl, nl+16)
    const float2 es0 = fsE[(head << 12) + n0 + nl];
    const float2 es1 = fsE[(head << 12) + n0 + 16 + nl];
    const unsigned char* ap0 = adjp + ((size_t)(n0 + nl) << 9);
    const unsigned char* ap1 = adjp + ((size_t)(n0 + 16 + nl) << 9);
    const float2* fde = fdE + (head << 12);
    const unsigned short* bbase = hBT + (size_t)(head * 128 + nl) * 4096 + quad * 8;
    U8 uo; uo.u = (uint4){0x3F803F80u, 0x3F803F80u, 0x3F803F80u, 0x3F803F80u};
    const short8 ones = uo.s;                    // bf16 1.0 — row-sum B operand
    f32x4 acc[2][8], accL[2];
#pragma unroll
    for (int rt = 0; rt < 2; rt++) {
        accL[rt] = (f32x4){0.f, 0.f, 0.f, 0.f};
#pragma unroll
        for (int ct = 0; ct < 8; ct++) acc[rt][ct] = (f32x4){0.f, 0.f, 0.f, 0.f};
    }
    short8 bcur[8], bnxt[8];
#pragma unroll
    for (int ct = 0; ct < 8; ct++)
        bcur[ct] = *(const short8*)(bbase + (size_t)ct * 65536 + m0base);
    for (int mc = 0; mc < 32; mc++) {
        const int m0 = m0base + mc * 32;
        // operand fetches
        const unsigned int bits0 = ap0[(m0 >> 3) + quad];
        const unsigned int bits1 = ap1[(m0 >> 3) + quad];
        union { float4 v[4]; float2 p[8]; } F;
        {
            const float4* fp = (const float4*)(fde + m0 + quad * 8);
            F.v[0] = fp[0]; F.v[1] = fp[1]; F.v[2] = fp[2]; F.v[3] = fp[3];
        }
        // prefetch next B chunk
        const int m0n = (mc < 31) ? m0 + 32 : m0base;
#pragma unroll
        for (int ct = 0; ct < 8; ct++)
            bnxt[ct] = *(const short8*)(bbase + (size_t)ct * 65536 + m0n);
        // weights -> A-frags (bf16, truncated)
        U8 af0, af1;
#pragma unroll
        for (int k = 0; k < 4; k++) {
            float w0[2], w1[2];
#pragma unroll
            for (int s = 0; s < 2; s++) {
                const int j = k * 2 + s;
                const float2 fp = F.p[j];
                float wa = fmaxf(es0.x * fp.x, es0.y * fp.y);
                float wb = fmaxf(es1.x * fp.x, es1.y * fp.y);
                w0[s] = __uint_as_float(__float_as_uint(wa) & bitmask1(bits0, j));
                w1[s] = __uint_as_float(__float_as_uint(wb) & bitmask1(bits1, j));
            }
            ((unsigned int*)&af0.u)[k] = pack_trunc(w0[0], w0[1]);
            ((unsigned int*)&af1.u)[k] = pack_trunc(w1[0], w1[1]);
        }
        // MFMAs: 16 PV + 2 row-sum
#pragma unroll
        for (int ct = 0; ct < 8; ct++) {
            acc[0][ct] = __builtin_amdgcn_mfma_f32_16x16x32_bf16(af0.s, bcur[ct], acc[0][ct], 0, 0, 0);
            acc[1][ct] = __builtin_amdgcn_mfma_f32_16x16x32_bf16(af1.s, bcur[ct], acc[1][ct], 0, 0, 0);
        }
        accL[0] = __builtin_amdgcn_mfma_f32_16x16x32_bf16(af0.s, ones, accL[0], 0, 0, 0);
        accL[1] = __builtin_amdgcn_mfma_f32_16x16x32_bf16(af1.s, ones, accL[1], 0, 0, 0);
#pragma unroll
        for (int ct = 0; ct < 8; ct++) bcur[ct] = bnxt[ct];
    }
    // ---- combine the 4 m-quarters ----
    // acc slot k=rt*8+ct owned by wave (ct&3); non-owners write partials.
#pragma unroll
    for (int rt = 0; rt < 2; rt++)
#pragma unroll
        for (int ct = 0; ct < 8; ct++) {
            const int owner = ct & 3;
            if (owner != wv) {
                const int j = (wv - owner - 1) & 3;
                cbuf[((rt * 8 + ct) * 3 + j) * 64 + lane] = acc[rt][ct];
            }
        }
#pragma unroll
    for (int rt = 0; rt < 2; rt++)
        cbuf[3072 + (rt * 4 + wv) * 64 + lane] = accL[rt];
    __syncthreads();
    // epilogue: wave wv finalizes cols ct = wv and wv+4
#pragma unroll
    for (int rt = 0; rt < 2; rt++) {
        f32x4 Lt = (f32x4){0.f, 0.f, 0.f, 0.f};
#pragma unroll
        for (int v = 0; v < 4; v++) Lt += cbuf[3072 + (rt * 4 + v) * 64 + lane];
        float iL[4];
#pragma unroll
        for (int r = 0; r < 4; r++) iL[r] = (Lt[r] > 0.f) ? (1.0f / Lt[r]) : 0.0f;
#pragma unroll
        for (int ci = 0; ci < 2; ci++) {
            const int ct = wv + ci * 4;
            const int k = rt * 8 + ct;
            f32x4 tot = acc[rt][ct];
#pragma unroll
            for (int j = 0; j < 3; j++) tot += cbuf[(k * 3 + j) * 64 + lane];
#pragma unroll
            for (int r = 0; r < 4; r++) {
                float v = tot[r] * iL[r];
                v = v > 0.f ? v : expm1f(v);   // ELU(alpha=1)
                out[(size_t)(n0 + rt * 16 + quad * 4 + r) * 512 + head * 128 + ct * 16 + nl] = v;
            }
        }
    }
}

extern "C" void kernel_launch(void* const* d_in, const int* in_sizes, int n_in,
                              void* d_out, int out_size, void* d_ws, size_t ws_size,
                              hipStream_t stream) {
    (void)in_sizes; (void)n_in; (void)out_size; (void)ws_size;
    const float* x   = (const float*)d_in[0];   // (4096,512) fp32
    const int*   adj = (const int*)d_in[1];     // (4096,4096) i32
    const float* W   = (const float*)d_in[2];   // (4,128,128) fp32
    const float* a   = (const float*)d_in[3];   // (4,256) fp32
    float* out = (float*)d_out;                 // (4096,512) fp32

    char* ws = (char*)d_ws;
    unsigned short* xbf  = (unsigned short*)(ws);                 // 4 MB
    unsigned short* hBT  = (unsigned short*)(ws + (4u << 20));    // 4 MB (H,128,4096)
    unsigned short* hamT = (unsigned short*)(ws + (8u << 20));    // 512 KB (H,128,512)
    unsigned char*  adjp = (unsigned char*)(ws + (9u << 20));     // 2 MB bitmask
    float2*         fsE  = (float2*)(ws + (11u << 20));           // 128 KB
    float2*         fdE  = (float2*)(ws + (11u << 20) + (128u << 10)); // 128 KB

    hipLaunchKernelGGL(k_xcvt, dim3(1024),    dim3(256), 0, stream, x, xbf);
    hipLaunchKernelGGL(k_ham,  dim3(128),     dim3(256), 0, stream, W, hamT);
    hipLaunchKernelGGL(k_pack, dim3(512),     dim3(256), 0, stream, adj, (unsigned long long*)adjp);
    hipLaunchKernelGGL(k_h,    dim3(64, 4),   dim3(256), 0, stream, xbf, hamT, a, hBT, fsE, fdE);
    hipLaunchKernelGGL(k_attn, dim3(128, 4),  dim3(256), 0, stream, adjp, fsE, fdE, hBT, out);
}

// Round 5
// 242.257 us; speedup vs baseline: 3.0077x; 1.0993x over previous
//
#include <hip/hip_runtime.h>
#include <math.h>

#define ALPHA 0.2f

typedef __attribute__((ext_vector_type(8))) short short8;
typedef __attribute__((ext_vector_type(4))) float f32x4;
typedef __attribute__((ext_vector_type(4))) int i32x4;

__device__ __forceinline__ unsigned short f2bf(float f) {
    unsigned int x = __float_as_uint(f);
    x += 0x7fffu + ((x >> 16) & 1u);   // RNE
    return (unsigned short)(x >> 16);
}
__device__ __forceinline__ unsigned int pack_rne(float lo, float hi) {
    return (unsigned int)f2bf(lo) | ((unsigned int)f2bf(hi) << 16);
}
// truncating bf16 pack (bias cancels in w/L since L sums the same truncated w)
__device__ __forceinline__ unsigned int pack_trunc(float lo, float hi) {
    return __builtin_amdgcn_perm(__float_as_uint(hi), __float_as_uint(lo), 0x07060302u);
}
// bit j of x -> 0x0 / 0xFFFFFFFF
__device__ __forceinline__ unsigned int bitmask1(unsigned int x, int j) {
    return (unsigned int)(((int)(x << (31 - j))) >> 31);
}

// ---------------------------------------------------------------------------
// K0 (fused prep): blocks [0,1024): x fp32->bf16. [1024,1152): hamilton
// transposed bf16 hamT[head][o][f]. [1152,1664): adj -> 1-bit mask.
// ---------------------------------------------------------------------------
__global__ __launch_bounds__(256) void k_prep(const float* __restrict__ x,
                                              const float* __restrict__ W,
                                              const int* __restrict__ adj,
                                              unsigned short* __restrict__ xbf,
                                              unsigned short* __restrict__ hamT,
                                              unsigned long long* __restrict__ adjp64) {
    const int b = blockIdx.x;
    if (b < 1024) {                       // ---- x convert: 2M elems, 8/thread
        const int gid = b * 256 + threadIdx.x;
        const float4* xp = (const float4*)x + (size_t)gid * 2;
        const float4 f0 = xp[0], f1 = xp[1];
        const uint4 o = {pack_rne(f0.x, f0.y), pack_rne(f0.z, f0.w),
                         pack_rne(f1.x, f1.y), pack_rne(f1.z, f1.w)};
        ((uint4*)xbf)[gid] = o;
    } else if (b < 1152) {                // ---- hamilton: sign mask 0x5390
        const int gid = (b - 1024) * 256 + threadIdx.x;    // 32768
        const int head = gid >> 13;
        const int rem  = gid & 8191;
        const int o = rem >> 6, f8 = rem & 63;
        const int ob = o >> 5, oc = o & 31;
        float v[8];
#pragma unroll
        for (int j = 0; j < 8; j++) {
            const int f = f8 * 8 + j;
            const int bq = f >> 7, f0 = f & 127;
            const float s = ((0x5390u >> ((bq << 2) | ob)) & 1u) ? -1.0f : 1.0f;
            v[j] = s * W[(head << 14) + (f0 << 7) + (((bq ^ ob) << 5) | oc)];
        }
        const uint4 pk = {pack_rne(v[0], v[1]), pack_rne(v[2], v[3]),
                          pack_rne(v[4], v[5]), pack_rne(v[6], v[7])};
        *(uint4*)(hamT + (size_t)(head * 128 + o) * 512 + f8 * 8) = pk;
    } else {                              // ---- adj bit-pack: 64 MB -> 2 MB
        const int wid  = (((b - 1152) * 256) + threadIdx.x) >> 6;   // 0..2047
        const int lane = threadIdx.x & 63;
        for (int i = wid; i < 262144; i += 2048) {
            const int v = adj[(size_t)i * 64 + lane];
            const unsigned long long mask = __ballot(v > 0);
            if (lane == 0) adjp64[i] = mask;
        }
    }
}

// ---------------------------------------------------------------------------
// K1: h = x @ ham via bf16 MFMA. Block: 4 waves x 16 rows, 128 cols, K=512.
// Outputs hBT[head][col][n] bf16 (B-layout for k_attn) and per-row softmax
// factors fsE=(exp(fs),exp(a*fs)), fdE=(exp(fd),exp(a*fd)) fp32.
// ---------------------------------------------------------------------------
__global__ __launch_bounds__(256) void k_h(const unsigned short* __restrict__ xbf,
                                           const unsigned short* __restrict__ hamT,
                                           const float* __restrict__ a,
                                           unsigned short* __restrict__ hBT,
                                           float2* __restrict__ fsE,
                                           float2* __restrict__ fdE) {
    const int t = threadIdx.x;
    const int head = blockIdx.y;
    const int n0 = blockIdx.x * 64;
    const int wv = t >> 6, lane = t & 63;
    const int quad = lane >> 4, nl = lane & 15;
    const unsigned short* ap = xbf + (size_t)(n0 + wv * 16 + nl) * 512 + quad * 8;
    const unsigned short* bp = hamT + (size_t)(head * 128 + nl) * 512 + quad * 8;
    f32x4 acc[8];
#pragma unroll
    for (int ct = 0; ct < 8; ct++) acc[ct] = (f32x4){0.f, 0.f, 0.f, 0.f};
    for (int kc = 0; kc < 16; kc++) {
        const short8 af = *(const short8*)(ap + kc * 32);
#pragma unroll
        for (int ct = 0; ct < 8; ct++) {
            const short8 bf_ = *(const short8*)(bp + (size_t)ct * 16 * 512 + kc * 32);
            acc[ct] = __builtin_amdgcn_mfma_f32_16x16x32_bf16(af, bf_, acc[ct], 0, 0, 0);
        }
    }
    const int rbase = n0 + wv * 16 + quad * 4;
#pragma unroll
    for (int ct = 0; ct < 8; ct++) {
        const uint2 pk = {pack_rne(acc[ct][0], acc[ct][1]), pack_rne(acc[ct][2], acc[ct][3])};
        *(uint2*)(hBT + (size_t)(head * 128 + ct * 16 + nl) * 4096 + rbase) = pk;
    }
    float fsr[4] = {0.f, 0.f, 0.f, 0.f}, fdr[4] = {0.f, 0.f, 0.f, 0.f};
#pragma unroll
    for (int ct = 0; ct < 8; ct++) {
        const int col = ct * 16 + nl;
        const float as = a[head * 256 + col];
        const float ad = a[head * 256 + 128 + col];
#pragma unroll
        for (int r = 0; r < 4; r++) {
            fsr[r] += acc[ct][r] * as;
            fdr[r] += acc[ct][r] * ad;
        }
    }
#pragma unroll
    for (int off = 1; off < 16; off <<= 1)
#pragma unroll
        for (int r = 0; r < 4; r++) {
            fsr[r] += __shfl_xor(fsr[r], off, 64);
            fdr[r] += __shfl_xor(fdr[r], off, 64);
        }
    if (nl == 0) {
#pragma unroll
        for (int r = 0; r < 4; r++) {
            const int n = rbase + r;
            fsE[(head << 12) + n] = make_float2(__expf(fsr[r]), __expf(ALPHA * fsr[r]));
            fdE[(head << 12) + n] = make_float2(__expf(fdr[r]), __expf(ALPHA * fdr[r]));
        }
    }
}

// ---------------------------------------------------------------------------
// K2: h' = softmax(mask(leaky(fs+fd))) @ h, fused ELU. No transcendentals in
// the N^2 path: exp(leaky(z)) = max(Es*Ed, Eas*Ead). Weights built in MFMA
// A-frag layout in REGISTERS; L via ones-B MFMA. All local arrays use
// compile-time indices only (scratch/alloca = the Round-4 101us bug).
// ---------------------------------------------------------------------------
#define WELT(e1, ea, j, bits, es) \
    __uint_as_float(__float_as_uint(fmaxf((es).x * (e1), (es).y * (ea))) & bitmask1((bits), (j)))
#define WPK(f4, jb, bits, es) \
    pack_trunc(WELT((f4).x, (f4).y, (jb), (bits), (es)), \
               WELT((f4).z, (f4).w, (jb) + 1, (bits), (es)))
#define BLOAD(ct, moff) (*(const short8*)(bbase + (size_t)(ct) * 65536 + (moff)))

__global__ __launch_bounds__(256, 2) void k_attn(const unsigned char* __restrict__ adjp,
                                                 const float2* __restrict__ fsE,
                                                 const float2* __restrict__ fdE,
                                                 const unsigned short* __restrict__ hBT,
                                                 float* __restrict__ out) {
    __shared__ f32x4 cbuf[3584];   // 16 acc-slots * 3 partials + 8 L slots, 56 KB
    const int t = threadIdx.x;
    const int head = blockIdx.y;
    const int n0 = blockIdx.x * 32;
    const int wv = t >> 6, lane = t & 63;
    const int quad = lane >> 4, nl = lane & 15;
    const int m0base = wv << 10;                 // this wave's m-quarter
    const float2 es0 = fsE[(head << 12) + n0 + nl];
    const float2 es1 = fsE[(head << 12) + n0 + 16 + nl];
    const unsigned char* ap0 = adjp + ((size_t)(n0 + nl) << 9) + (m0base >> 3) + quad;
    const unsigned char* ap1 = ap0 + (16u << 9);
    const float4* fdb = (const float4*)(fdE + (head << 12) + m0base + quad * 8);
    const unsigned short* bbase = hBT + (size_t)(head * 128 + nl) * 4096 + quad * 8 + m0base;
    const short8 ones = __builtin_bit_cast(short8,
        (i32x4){0x3F803F80, 0x3F803F80, 0x3F803F80, 0x3F803F80});
    f32x4 acc[2][8];
    f32x4 accL0 = (f32x4){0.f, 0.f, 0.f, 0.f}, accL1 = (f32x4){0.f, 0.f, 0.f, 0.f};
#pragma unroll
    for (int rt = 0; rt < 2; rt++)
#pragma unroll
        for (int ct = 0; ct < 8; ct++) acc[rt][ct] = (f32x4){0.f, 0.f, 0.f, 0.f};
    short8 bc[8];
#pragma unroll
    for (int ct = 0; ct < 8; ct++) bc[ct] = BLOAD(ct, 0);
    unsigned int bits0 = ap0[0], bits1 = ap1[0];
    float4 fA = fdb[0], fB = fdb[1], fC = fdb[2], fD = fdb[3];
#pragma unroll 2
    for (int mc = 0; mc < 32; mc++) {
        const int mcn = (mc + 1) & 31;           // wrap load harmless
        const int mo  = mcn * 32;
        short8 bn[8];
#pragma unroll
        for (int ct = 0; ct < 8; ct++) bn[ct] = BLOAD(ct, mo);
        const unsigned int nb0 = ap0[mcn * 4], nb1 = ap1[mcn * 4];
        const float4 nfA = fdb[mcn * 16], nfB = fdb[mcn * 16 + 1];
        const float4 nfC = fdb[mcn * 16 + 2], nfD = fdb[mcn * 16 + 3];
        const i32x4 a0i = {(int)WPK(fA, 0, bits0, es0), (int)WPK(fB, 2, bits0, es0),
                           (int)WPK(fC, 4, bits0, es0), (int)WPK(fD, 6, bits0, es0)};
        const i32x4 a1i = {(int)WPK(fA, 0, bits1, es1), (int)WPK(fB, 2, bits1, es1),
                           (int)WPK(fC, 4, bits1, es1), (int)WPK(fD, 6, bits1, es1)};
        const short8 af0 = __builtin_bit_cast(short8, a0i);
        const short8 af1 = __builtin_bit_cast(short8, a1i);
#pragma unroll
        for (int ct = 0; ct < 8; ct++) {
            acc[0][ct] = __builtin_amdgcn_mfma_f32_16x16x32_bf16(af0, bc[ct], acc[0][ct], 0, 0, 0);
            acc[1][ct] = __builtin_amdgcn_mfma_f32_16x16x32_bf16(af1, bc[ct], acc[1][ct], 0, 0, 0);
        }
        accL0 = __builtin_amdgcn_mfma_f32_16x16x32_bf16(af0, ones, accL0, 0, 0, 0);
        accL1 = __builtin_amdgcn_mfma_f32_16x16x32_bf16(af1, ones, accL1, 0, 0, 0);
#pragma unroll
        for (int ct = 0; ct < 8; ct++) bc[ct] = bn[ct];
        bits0 = nb0; bits1 = nb1; fA = nfA; fB = nfB; fC = nfC; fD = nfD;
    }
    // ---- combine 4 m-quarters (acc slot (rt,ct) owned by wave ct&3) ----
#pragma unroll
    for (int rt = 0; rt < 2; rt++)
#pragma unroll
        for (int ct = 0; ct < 8; ct++) {
            const int owner = ct & 3;
            if (owner != wv) {
                const int j = (wv - owner - 1) & 3;
                cbuf[((rt * 8 + ct) * 3 + j) * 64 + lane] = acc[rt][ct];
            }
        }
    cbuf[3072 + wv * 64 + lane] = accL0;
    cbuf[3072 + (4 + wv) * 64 + lane] = accL1;
    __syncthreads();
#pragma unroll
    for (int rt = 0; rt < 2; rt++) {
        f32x4 Lt = (f32x4){0.f, 0.f, 0.f, 0.f};
#pragma unroll
        for (int v = 0; v < 4; v++) Lt += cbuf[3072 + (rt * 4 + v) * 64 + lane];
        float iL[4];
#pragma unroll
        for (int r = 0; r < 4; r++) iL[r] = (Lt[r] > 0.f) ? (1.0f / Lt[r]) : 0.0f;
#pragma unroll
        for (int ct = 0; ct < 8; ct++) {
            if ((ct & 3) == wv) {                // wave-uniform; ct stays constant
                f32x4 tot = acc[rt][ct];
#pragma unroll
                for (int j = 0; j < 3; j++) tot += cbuf[((rt * 8 + ct) * 3 + j) * 64 + lane];
#pragma unroll
                for (int r = 0; r < 4; r++) {
                    float v = tot[r] * iL[r];
                    v = v > 0.f ? v : (__expf(v) - 1.0f);   // ELU(alpha=1)
                    out[(size_t)(n0 + rt * 16 + quad * 4 + r) * 512
                        + head * 128 + ct * 16 + nl] = v;
                }
            }
        }
    }
}

extern "C" void kernel_launch(void* const* d_in, const int* in_sizes, int n_in,
                              void* d_out, int out_size, void* d_ws, size_t ws_size,
                              hipStream_t stream) {
    (void)in_sizes; (void)n_in; (void)out_size; (void)ws_size;
    const float* x   = (const float*)d_in[0];   // (4096,512) fp32
    const int*   adj = (const int*)d_in[1];     // (4096,4096) i32
    const float* W   = (const float*)d_in[2];   // (4,128,128) fp32
    const float* a   = (const float*)d_in[3];   // (4,256) fp32
    float* out = (float*)d_out;                 // (4096,512) fp32

    char* ws = (char*)d_ws;
    unsigned short* xbf  = (unsigned short*)(ws);                 // 4 MB
    unsigned short* hBT  = (unsigned short*)(ws + (4u << 20));    // 4 MB (H,128,4096)
    unsigned short* hamT = (unsigned short*)(ws + (8u << 20));    // 512 KB (H,128,512)
    unsigned char*  adjp = (unsigned char*)(ws + (9u << 20));     // 2 MB bitmask
    float2*         fsE  = (float2*)(ws + (11u << 20));           // 128 KB
    float2*         fdE  = (float2*)(ws + (11u << 20) + (128u << 10)); // 128 KB

    hipLaunchKernelGGL(k_prep, dim3(1664),    dim3(256), 0, stream,
                       x, W, adj, xbf, hamT, (unsigned long long*)adjp);
    hipLaunchKernelGGL(k_h,    dim3(64, 4),   dim3(256), 0, stream, xbf, hamT, a, hBT, fsE, fdE);
    hipLaunchKernelGGL(k_attn, dim3(128, 4),  dim3(256), 0, stream, adjp, fsE, fdE, hBT, out);
}

// Round 7
// 222.334 us; speedup vs baseline: 3.2772x; 1.0896x over previous
//
#include <hip/hip_runtime.h>
#include <math.h>

#define ALPHA 0.2f

// Padded strides: odd multiples of 64B lines to kill L1 set-aliasing
// (power-of-2 col strides put every line of a wave's load in ONE L1 set).
#define XS   544    // xbf / hamT row stride in shorts (17 lines)
#define HS   4128   // hBT col stride in shorts (129 lines)
#define HCS  66048  // 16 cols * HS

typedef __attribute__((ext_vector_type(8))) short short8;
typedef __attribute__((ext_vector_type(4))) float f32x4;
typedef __attribute__((ext_vector_type(4))) int i32x4;

__device__ __forceinline__ unsigned short f2bf(float f) {
    unsigned int x = __float_as_uint(f);
    x += 0x7fffu + ((x >> 16) & 1u);   // RNE
    return (unsigned short)(x >> 16);
}
__device__ __forceinline__ unsigned int pack_rne(float lo, float hi) {
    return (unsigned int)f2bf(lo) | ((unsigned int)f2bf(hi) << 16);
}
// truncating bf16 pack (bias cancels in w/L since L sums the same truncated w)
__device__ __forceinline__ unsigned int pack_trunc(float lo, float hi) {
    return __builtin_amdgcn_perm(__float_as_uint(hi), __float_as_uint(lo), 0x07060302u);
}
// bit j of x -> 0x0 / 0xFFFFFFFF
__device__ __forceinline__ unsigned int bitmask1(unsigned int x, int j) {
    return (unsigned int)(((int)(x << (31 - j))) >> 31);
}

// ---------------------------------------------------------------------------
// K0 (fused prep): [0,1024): x fp32->bf16 (padded rows). [1024,1152):
// hamilton transposed bf16 hamT[head][o][f] (padded). [1152,1664): adj->bits.
// ---------------------------------------------------------------------------
__global__ __launch_bounds__(256) void k_prep(const float* __restrict__ x,
                                              const float* __restrict__ W,
                                              const int* __restrict__ adj,
                                              unsigned short* __restrict__ xbf,
                                              unsigned short* __restrict__ hamT,
                                              unsigned long long* __restrict__ adjp64) {
    const int b = blockIdx.x;
    if (b < 1024) {                       // ---- x convert: 2M elems, 8/thread
        const int gid = b * 256 + threadIdx.x;
        const int row = gid >> 6, c8 = (gid & 63) * 8;
        const float4* xp = (const float4*)x + (size_t)gid * 2;
        const float4 f0 = xp[0], f1 = xp[1];
        const uint4 o = {pack_rne(f0.x, f0.y), pack_rne(f0.z, f0.w),
                         pack_rne(f1.x, f1.y), pack_rne(f1.z, f1.w)};
        *(uint4*)(xbf + (size_t)row * XS + c8) = o;
    } else if (b < 1152) {                // ---- hamilton: sign mask 0x5390
        const int gid = (b - 1024) * 256 + threadIdx.x;    // 32768
        const int head = gid >> 13;
        const int rem  = gid & 8191;
        const int o = rem >> 6, f8 = rem & 63;
        const int ob = o >> 5, oc = o & 31;
        float v[8];
#pragma unroll
        for (int j = 0; j < 8; j++) {
            const int f = f8 * 8 + j;
            const int bq = f >> 7, f0 = f & 127;
            const float s = ((0x5390u >> ((bq << 2) | ob)) & 1u) ? -1.0f : 1.0f;
            v[j] = s * W[(head << 14) + (f0 << 7) + (((bq ^ ob) << 5) | oc)];
        }
        const uint4 pk = {pack_rne(v[0], v[1]), pack_rne(v[2], v[3]),
                          pack_rne(v[4], v[5]), pack_rne(v[6], v[7])};
        *(uint4*)(hamT + (size_t)(head * 128 + o) * XS + f8 * 8) = pk;
    } else {                              // ---- adj bit-pack: 64 MB -> 2 MB
        const int wid  = (((b - 1152) * 256) + threadIdx.x) >> 6;   // 0..2047
        const int lane = threadIdx.x & 63;
        for (int i = wid; i < 262144; i += 2048) {
            const int v = adj[(size_t)i * 64 + lane];
            const unsigned long long mask = __ballot(v > 0);
            if (lane == 0) adjp64[i] = mask;
        }
    }
}

// ---------------------------------------------------------------------------
// K1: h = x @ ham via bf16 MFMA — Round-5 structure verbatim (passed), only
// strides adapted (512->XS, 4096->HS). Block: 4 waves x 16 rows, 128 cols.
// ---------------------------------------------------------------------------
__global__ __launch_bounds__(256) void k_h(const unsigned short* __restrict__ xbf,
                                           const unsigned short* __restrict__ hamT,
                                           const float* __restrict__ a,
                                           unsigned short* __restrict__ hBT,
                                           float2* __restrict__ fsE,
                                           float2* __restrict__ fdE) {
    const int t = threadIdx.x;
    const int head = blockIdx.y;
    const int n0 = blockIdx.x * 64;
    const int wv = t >> 6, lane = t & 63;
    const int quad = lane >> 4, nl = lane & 15;
    const unsigned short* ap = xbf + (size_t)(n0 + wv * 16 + nl) * XS + quad * 8;
    const unsigned short* bp = hamT + (size_t)(head * 128 + nl) * XS + quad * 8;
    f32x4 acc[8];
#pragma unroll
    for (int ct = 0; ct < 8; ct++) acc[ct] = (f32x4){0.f, 0.f, 0.f, 0.f};
    for (int kc = 0; kc < 16; kc++) {
        const short8 af = *(const short8*)(ap + kc * 32);
#pragma unroll
        for (int ct = 0; ct < 8; ct++) {
            const short8 bf_ = *(const short8*)(bp + (size_t)ct * 16 * XS + kc * 32);
            acc[ct] = __builtin_amdgcn_mfma_f32_16x16x32_bf16(af, bf_, acc[ct], 0, 0, 0);
        }
    }
    const int rbase = n0 + wv * 16 + quad * 4;
#pragma unroll
    for (int ct = 0; ct < 8; ct++) {
        const uint2 pk = {pack_rne(acc[ct][0], acc[ct][1]), pack_rne(acc[ct][2], acc[ct][3])};
        *(uint2*)(hBT + (size_t)(head * 128 + ct * 16 + nl) * HS + rbase) = pk;
    }
    float fsr[4] = {0.f, 0.f, 0.f, 0.f}, fdr[4] = {0.f, 0.f, 0.f, 0.f};
#pragma unroll
    for (int ct = 0; ct < 8; ct++) {
        const int col = ct * 16 + nl;
        const float as = a[head * 256 + col];
        const float ad = a[head * 256 + 128 + col];
#pragma unroll
        for (int r = 0; r < 4; r++) {
            fsr[r] += acc[ct][r] * as;
            fdr[r] += acc[ct][r] * ad;
        }
    }
#pragma unroll
    for (int off = 1; off < 16; off <<= 1)
#pragma unroll
        for (int r = 0; r < 4; r++) {
            fsr[r] += __shfl_xor(fsr[r], off, 64);
            fdr[r] += __shfl_xor(fdr[r], off, 64);
        }
    if (nl == 0) {
#pragma unroll
        for (int r = 0; r < 4; r++) {
            const int n = rbase + r;
            fsE[(head << 12) + n] = make_float2(__expf(fsr[r]), __expf(ALPHA * fsr[r]));
            fdE[(head << 12) + n] = make_float2(__expf(fdr[r]), __expf(ALPHA * fdr[r]));
        }
    }
}

// ---------------------------------------------------------------------------
// K2: h' = softmax(mask(leaky(fs+fd))) @ h, fused ELU. No transcendentals in
// the N^2 path: exp(leaky(z)) = max(Es*Ed, Eas*Ead). Weights in MFMA A-frag
// layout in registers; L via ones-B MFMA; compile-time indices only.
// ---------------------------------------------------------------------------
#define WELT(e1, ea, j, bits, es) \
    __uint_as_float(__float_as_uint(fmaxf((es).x * (e1), (es).y * (ea))) & bitmask1((bits), (j)))
#define WPK(f4, jb, bits, es) \
    pack_trunc(WELT((f4).x, (f4).y, (jb), (bits), (es)), \
               WELT((f4).z, (f4).w, (jb) + 1, (bits), (es)))
#define BLOAD(ct, moff) (*(const short8*)(bbase + (size_t)(ct) * HCS + (moff)))

__global__ __launch_bounds__(256, 2) void k_attn(const unsigned char* __restrict__ adjp,
                                                 const float2* __restrict__ fsE,
                                                 const float2* __restrict__ fdE,
                                                 const unsigned short* __restrict__ hBT,
                                                 float* __restrict__ out) {
    __shared__ f32x4 cbuf[3584];   // 16 acc-slots * 3 partials + 8 L slots, 56 KB
    const int t = threadIdx.x;
    const int head = blockIdx.y;
    const int n0 = blockIdx.x * 32;
    const int wv = t >> 6, lane = t & 63;
    const int quad = lane >> 4, nl = lane & 15;
    const int m0base = wv << 10;                 // this wave's m-quarter
    const float2 es0 = fsE[(head << 12) + n0 + nl];
    const float2 es1 = fsE[(head << 12) + n0 + 16 + nl];
    const unsigned char* ap0 = adjp + ((size_t)(n0 + nl) << 9) + (m0base >> 3) + quad;
    const unsigned char* ap1 = ap0 + (16u << 9);
    const float4* fdb = (const float4*)(fdE + (head << 12) + m0base + quad * 8);
    const unsigned short* bbase = hBT + (size_t)(head * 128 + nl) * HS + quad * 8 + m0base;
    const short8 ones = __builtin_bit_cast(short8,
        (i32x4){0x3F803F80, 0x3F803F80, 0x3F803F80, 0x3F803F80});
    f32x4 acc[2][8];
    f32x4 accL0 = (f32x4){0.f, 0.f, 0.f, 0.f}, accL1 = (f32x4){0.f, 0.f, 0.f, 0.f};
#pragma unroll
    for (int rt = 0; rt < 2; rt++)
#pragma unroll
        for (int ct = 0; ct < 8; ct++) acc[rt][ct] = (f32x4){0.f, 0.f, 0.f, 0.f};
    short8 bc[8];
#pragma unroll
    for (int ct = 0; ct < 8; ct++) bc[ct] = BLOAD(ct, 0);
    unsigned int bits0 = ap0[0], bits1 = ap1[0];
    float4 fA = fdb[0], fB = fdb[1], fC = fdb[2], fD = fdb[3];
#pragma unroll 2
    for (int mc = 0; mc < 32; mc++) {
        const int mcn = (mc + 1) & 31;           // wrap load harmless
        const int mo  = mcn * 32;
        short8 bn[8];
#pragma unroll
        for (int ct = 0; ct < 8; ct++) bn[ct] = BLOAD(ct, mo);
        const unsigned int nb0 = ap0[mcn * 4], nb1 = ap1[mcn * 4];
        const float4 nfA = fdb[mcn * 16], nfB = fdb[mcn * 16 + 1];
        const float4 nfC = fdb[mcn * 16 + 2], nfD = fdb[mcn * 16 + 3];
        const i32x4 a0i = {(int)WPK(fA, 0, bits0, es0), (int)WPK(fB, 2, bits0, es0),
                           (int)WPK(fC, 4, bits0, es0), (int)WPK(fD, 6, bits0, es0)};
        const i32x4 a1i = {(int)WPK(fA, 0, bits1, es1), (int)WPK(fB, 2, bits1, es1),
                           (int)WPK(fC, 4, bits1, es1), (int)WPK(fD, 6, bits1, es1)};
        const short8 af0 = __builtin_bit_cast(short8, a0i);
        const short8 af1 = __builtin_bit_cast(short8, a1i);
#pragma unroll
        for (int ct = 0; ct < 8; ct++) {
            acc[0][ct] = __builtin_amdgcn_mfma_f32_16x16x32_bf16(af0, bc[ct], acc[0][ct], 0, 0, 0);
            acc[1][ct] = __builtin_amdgcn_mfma_f32_16x16x32_bf16(af1, bc[ct], acc[1][ct], 0, 0, 0);
        }
        accL0 = __builtin_amdgcn_mfma_f32_16x16x32_bf16(af0, ones, accL0, 0, 0, 0);
        accL1 = __builtin_amdgcn_mfma_f32_16x16x32_bf16(af1, ones, accL1, 0, 0, 0);
#pragma unroll
        for (int ct = 0; ct < 8; ct++) bc[ct] = bn[ct];
        bits0 = nb0; bits1 = nb1; fA = nfA; fB = nfB; fC = nfC; fD = nfD;
    }
    // ---- combine 4 m-quarters (acc slot (rt,ct) owned by wave ct&3) ----
#pragma unroll
    for (int rt = 0; rt < 2; rt++)
#pragma unroll
        for (int ct = 0; ct < 8; ct++) {
            const int owner = ct & 3;
            if (owner != wv) {
                const int j = (wv - owner - 1) & 3;
                cbuf[((rt * 8 + ct) * 3 + j) * 64 + lane] = acc[rt][ct];
            }
        }
    cbuf[3072 + wv * 64 + lane] = accL0;
    cbuf[3072 + (4 + wv) * 64 + lane] = accL1;
    __syncthreads();
#pragma unroll
    for (int rt = 0; rt < 2; rt++) {
        f32x4 Lt = (f32x4){0.f, 0.f, 0.f, 0.f};
#pragma unroll
        for (int v = 0; v < 4; v++) Lt += cbuf[3072 + (rt * 4 + v) * 64 + lane];
        float iL[4];
#pragma unroll
        for (int r = 0; r < 4; r++) iL[r] = (Lt[r] > 0.f) ? (1.0f / Lt[r]) : 0.0f;
#pragma unroll
        for (int ct = 0; ct < 8; ct++) {
            if ((ct & 3) == wv) {                // wave-uniform; ct stays constant
                f32x4 tot = acc[rt][ct];
#pragma unroll
                for (int j = 0; j < 3; j++) tot += cbuf[((rt * 8 + ct) * 3 + j) * 64 + lane];
#pragma unroll
                for (int r = 0; r < 4; r++) {
                    float v = tot[r] * iL[r];
                    v = v > 0.f ? v : (__expf(v) - 1.0f);   // ELU(alpha=1)
                    out[(size_t)(n0 + rt * 16 + quad * 4 + r) * 512
                        + head * 128 + ct * 16 + nl] = v;
                }
            }
        }
    }
}

extern "C" void kernel_launch(void* const* d_in, const int* in_sizes, int n_in,
                              void* d_out, int out_size, void* d_ws, size_t ws_size,
                              hipStream_t stream) {
    (void)in_sizes; (void)n_in; (void)out_size; (void)ws_size;
    const float* x   = (const float*)d_in[0];   // (4096,512) fp32
    const int*   adj = (const int*)d_in[1];     // (4096,4096) i32
    const float* W   = (const float*)d_in[2];   // (4,128,128) fp32
    const float* a   = (const float*)d_in[3];   // (4,256) fp32
    float* out = (float*)d_out;                 // (4096,512) fp32

    char* ws = (char*)d_ws;
    unsigned short* xbf  = (unsigned short*)(ws);             // 4096*544*2 = 4456448
    unsigned short* hBT  = (unsigned short*)(ws + 4456448);   // 4*128*4128*2 = 4227072
    unsigned short* hamT = (unsigned short*)(ws + 8683520);   // 4*128*544*2 = 557056
    unsigned char*  adjp = (unsigned char*)(ws + 9240576);    // 2 MB bitmask
    float2*         fsE  = (float2*)(ws + 11337728);          // 128 KB
    float2*         fdE  = (float2*)(ws + 11468800);          // 128 KB

    hipLaunchKernelGGL(k_prep, dim3(1664),    dim3(256), 0, stream,
                       x, W, adj, xbf, hamT, (unsigned long long*)adjp);
    hipLaunchKernelGGL(k_h,    dim3(64, 4),   dim3(256), 0, stream, xbf, hamT, a, hBT, fsE, fdE);
    hipLaunchKernelGGL(k_attn, dim3(128, 4),  dim3(256), 0, stream, adjp, fsE, fdE, hBT, out);
}

// Round 8
// 176.762 us; speedup vs baseline: 4.1221x; 1.2578x over previous
//
#include <hip/hip_runtime.h>
#include <math.h>

#define ALPHA 0.2f

// Padded strides: odd multiples of 64B lines to kill L1 set-aliasing
#define XS   544    // xbf / hamT row stride in shorts (17 lines)
#define HS   4128   // hBT col stride in shorts (129 lines)
#define HCS  66048  // 16 cols * HS

typedef __attribute__((ext_vector_type(8))) short short8;
typedef __attribute__((ext_vector_type(4))) float f32x4;
typedef __attribute__((ext_vector_type(4))) int i32x4;

__device__ __forceinline__ unsigned short f2bf(float f) {
    unsigned int x = __float_as_uint(f);
    x += 0x7fffu + ((x >> 16) & 1u);   // RNE
    return (unsigned short)(x >> 16);
}
__device__ __forceinline__ unsigned int pack_rne(float lo, float hi) {
    return (unsigned int)f2bf(lo) | ((unsigned int)f2bf(hi) << 16);
}
// truncating bf16 pack (bias cancels in w/L since L sums the same truncated w)
__device__ __forceinline__ unsigned int pack_trunc(float lo, float hi) {
    return __builtin_amdgcn_perm(__float_as_uint(hi), __float_as_uint(lo), 0x07060302u);
}
// bit j of x -> 0x0 / 0xFFFFFFFF
__device__ __forceinline__ unsigned int bitmask1(unsigned int x, int j) {
    return (unsigned int)(((int)(x << (31 - j))) >> 31);
}

// ---------------------------------------------------------------------------
// K0 (fused prep): [0,1024): x fp32->bf16 (padded rows). [1024,1152):
// hamilton transposed bf16. [1152,3200): adj -> 1-bit mask, 32 adj/thread via
// 8 independent dwordx4 loads (deep MLP; the old 1-word-per-wave ballot loop
// was latency-serialized at 74us).
// ---------------------------------------------------------------------------
__global__ __launch_bounds__(256) void k_prep(const float* __restrict__ x,
                                              const float* __restrict__ W,
                                              const int* __restrict__ adj,
                                              unsigned short* __restrict__ xbf,
                                              unsigned short* __restrict__ hamT,
                                              unsigned int* __restrict__ adjp32) {
    const int b = blockIdx.x;
    if (b < 1024) {                       // ---- x convert: 2M elems, 8/thread
        const int gid = b * 256 + threadIdx.x;
        const int row = gid >> 6, c8 = (gid & 63) * 8;
        const float4* xp = (const float4*)x + (size_t)gid * 2;
        const float4 f0 = xp[0], f1 = xp[1];
        const uint4 o = {pack_rne(f0.x, f0.y), pack_rne(f0.z, f0.w),
                         pack_rne(f1.x, f1.y), pack_rne(f1.z, f1.w)};
        *(uint4*)(xbf + (size_t)row * XS + c8) = o;
    } else if (b < 1152) {                // ---- hamilton: sign mask 0x5390
        const int gid = (b - 1024) * 256 + threadIdx.x;    // 32768
        const int head = gid >> 13;
        const int rem  = gid & 8191;
        const int o = rem >> 6, f8 = rem & 63;
        const int ob = o >> 5, oc = o & 31;
        float v[8];
#pragma unroll
        for (int j = 0; j < 8; j++) {
            const int f = f8 * 8 + j;
            const int bq = f >> 7, f0 = f & 127;
            const float s = ((0x5390u >> ((bq << 2) | ob)) & 1u) ? -1.0f : 1.0f;
            v[j] = s * W[(head << 14) + (f0 << 7) + (((bq ^ ob) << 5) | oc)];
        }
        const uint4 pk = {pack_rne(v[0], v[1]), pack_rne(v[2], v[3]),
                          pack_rne(v[4], v[5]), pack_rne(v[6], v[7])};
        *(uint4*)(hamT + (size_t)(head * 128 + o) * XS + f8 * 8) = pk;
    } else {                              // ---- adj bit-pack: 64 MB -> 2 MB
        const int gid = (b - 1152) * 256 + threadIdx.x;    // 0..524287
        const int4* ap = (const int4*)(adj + (size_t)gid * 32);
        unsigned int u = 0;
#pragma unroll
        for (int q = 0; q < 8; q++) {
            const int4 v = ap[q];
            u |= (v.x > 0 ? 1u : 0u) << (q * 4);
            u |= (v.y > 0 ? 2u : 0u) << (q * 4);
            u |= (v.z > 0 ? 4u : 0u) << (q * 4);
            u |= (v.w > 0 ? 8u : 0u) << (q * 4);
        }
        adjp32[gid] = u;
    }
}

// ---------------------------------------------------------------------------
// K1: h = x @ ham via bf16 MFMA (Round-5 structure, passed). Block: 4 waves
// x 16 rows, 128 cols. Outputs hBT (padded col-major bf16) + fsE/fdE.
// ---------------------------------------------------------------------------
__global__ __launch_bounds__(256) void k_h(const unsigned short* __restrict__ xbf,
                                           const unsigned short* __restrict__ hamT,
                                           const float* __restrict__ a,
                                           unsigned short* __restrict__ hBT,
                                           float2* __restrict__ fsE,
                                           float2* __restrict__ fdE) {
    const int t = threadIdx.x;
    const int head = blockIdx.y;
    const int n0 = blockIdx.x * 64;
    const int wv = t >> 6, lane = t & 63;
    const int quad = lane >> 4, nl = lane & 15;
    const unsigned short* ap = xbf + (size_t)(n0 + wv * 16 + nl) * XS + quad * 8;
    const unsigned short* bp = hamT + (size_t)(head * 128 + nl) * XS + quad * 8;
    f32x4 acc[8];
#pragma unroll
    for (int ct = 0; ct < 8; ct++) acc[ct] = (f32x4){0.f, 0.f, 0.f, 0.f};
    for (int kc = 0; kc < 16; kc++) {
        const short8 af = *(const short8*)(ap + kc * 32);
#pragma unroll
        for (int ct = 0; ct < 8; ct++) {
            const short8 bf_ = *(const short8*)(bp + (size_t)ct * 16 * XS + kc * 32);
            acc[ct] = __builtin_amdgcn_mfma_f32_16x16x32_bf16(af, bf_, acc[ct], 0, 0, 0);
        }
    }
    const int rbase = n0 + wv * 16 + quad * 4;
#pragma unroll
    for (int ct = 0; ct < 8; ct++) {
        const uint2 pk = {pack_rne(acc[ct][0], acc[ct][1]), pack_rne(acc[ct][2], acc[ct][3])};
        *(uint2*)(hBT + (size_t)(head * 128 + ct * 16 + nl) * HS + rbase) = pk;
    }
    float fsr[4] = {0.f, 0.f, 0.f, 0.f}, fdr[4] = {0.f, 0.f, 0.f, 0.f};
#pragma unroll
    for (int ct = 0; ct < 8; ct++) {
        const int col = ct * 16 + nl;
        const float as = a[head * 256 + col];
        const float ad = a[head * 256 + 128 + col];
#pragma unroll
        for (int r = 0; r < 4; r++) {
            fsr[r] += acc[ct][r] * as;
            fdr[r] += acc[ct][r] * ad;
        }
    }
#pragma unroll
    for (int off = 1; off < 16; off <<= 1)
#pragma unroll
        for (int r = 0; r < 4; r++) {
            fsr[r] += __shfl_xor(fsr[r], off, 64);
            fdr[r] += __shfl_xor(fdr[r], off, 64);
        }
    if (nl == 0) {
#pragma unroll
        for (int r = 0; r < 4; r++) {
            const int n = rbase + r;
            fsE[(head << 12) + n] = make_float2(__expf(fsr[r]), __expf(ALPHA * fsr[r]));
            fdE[(head << 12) + n] = make_float2(__expf(fdr[r]), __expf(ALPHA * fdr[r]));
        }
    }
}

// ---------------------------------------------------------------------------
// K2: h' = softmax(mask(leaky(fs+fd))) @ h, fused ELU.
// Even/odd software pipeline (no register copy chain -> real 1-stage prefetch
// distance). Head pinned per XCD via head=blockIdx.x&3 (round-robin dispatch)
// so each XCD's L2 working set is ~3.1 MB < 4 MB (FETCH showed 2.6x re-fetch).
// ---------------------------------------------------------------------------
#define WELT(e1, ea, j, bits, es) \
    __uint_as_float(__float_as_uint(fmaxf((es).x * (e1), (es).y * (ea))) & bitmask1((bits), (j)))
#define WPK(f4, jb, bits, es) \
    pack_trunc(WELT((f4).x, (f4).y, (jb), (bits), (es)), \
               WELT((f4).z, (f4).w, (jb) + 1, (bits), (es)))
#define BLOAD(ct, moff) (*(const short8*)(bbase + (size_t)(ct) * HCS + (moff)))

#define STAGE_LOAD(P, mcn) do {                                           \
    const int _mo = (mcn) * 32;                                           \
    P##b0 = BLOAD(0, _mo); P##b1 = BLOAD(1, _mo);                         \
    P##b2 = BLOAD(2, _mo); P##b3 = BLOAD(3, _mo);                         \
    P##b4 = BLOAD(4, _mo); P##b5 = BLOAD(5, _mo);                         \
    P##b6 = BLOAD(6, _mo); P##b7 = BLOAD(7, _mo);                         \
    P##k0 = ap0[(mcn) * 4]; P##k1 = ap1[(mcn) * 4];                       \
    P##f0 = fdb[(mcn) * 16];     P##f1 = fdb[(mcn) * 16 + 1];             \
    P##f2 = fdb[(mcn) * 16 + 2]; P##f3 = fdb[(mcn) * 16 + 3];             \
} while (0)

#define STAGE_EXEC(P) do {                                                \
    const i32x4 _a0 = {(int)WPK(P##f0, 0, P##k0, es0), (int)WPK(P##f1, 2, P##k0, es0), \
                       (int)WPK(P##f2, 4, P##k0, es0), (int)WPK(P##f3, 6, P##k0, es0)}; \
    const i32x4 _a1 = {(int)WPK(P##f0, 0, P##k1, es1), (int)WPK(P##f1, 2, P##k1, es1), \
                       (int)WPK(P##f2, 4, P##k1, es1), (int)WPK(P##f3, 6, P##k1, es1)}; \
    const short8 _af0 = __builtin_bit_cast(short8, _a0);                  \
    const short8 _af1 = __builtin_bit_cast(short8, _a1);                  \
    acc[0][0] = __builtin_amdgcn_mfma_f32_16x16x32_bf16(_af0, P##b0, acc[0][0], 0, 0, 0); \
    acc[1][0] = __builtin_amdgcn_mfma_f32_16x16x32_bf16(_af1, P##b0, acc[1][0], 0, 0, 0); \
    acc[0][1] = __builtin_amdgcn_mfma_f32_16x16x32_bf16(_af0, P##b1, acc[0][1], 0, 0, 0); \
    acc[1][1] = __builtin_amdgcn_mfma_f32_16x16x32_bf16(_af1, P##b1, acc[1][1], 0, 0, 0); \
    acc[0][2] = __builtin_amdgcn_mfma_f32_16x16x32_bf16(_af0, P##b2, acc[0][2], 0, 0, 0); \
    acc[1][2] = __builtin_amdgcn_mfma_f32_16x16x32_bf16(_af1, P##b2, acc[1][2], 0, 0, 0); \
    acc[0][3] = __builtin_amdgcn_mfma_f32_16x16x32_bf16(_af0, P##b3, acc[0][3], 0, 0, 0); \
    acc[1][3] = __builtin_amdgcn_mfma_f32_16x16x32_bf16(_af1, P##b3, acc[1][3], 0, 0, 0); \
    acc[0][4] = __builtin_amdgcn_mfma_f32_16x16x32_bf16(_af0, P##b4, acc[0][4], 0, 0, 0); \
    acc[1][4] = __builtin_amdgcn_mfma_f32_16x16x32_bf16(_af1, P##b4, acc[1][4], 0, 0, 0); \
    acc[0][5] = __builtin_amdgcn_mfma_f32_16x16x32_bf16(_af0, P##b5, acc[0][5], 0, 0, 0); \
    acc[1][5] = __builtin_amdgcn_mfma_f32_16x16x32_bf16(_af1, P##b5, acc[1][5], 0, 0, 0); \
    acc[0][6] = __builtin_amdgcn_mfma_f32_16x16x32_bf16(_af0, P##b6, acc[0][6], 0, 0, 0); \
    acc[1][6] = __builtin_amdgcn_mfma_f32_16x16x32_bf16(_af1, P##b6, acc[1][6], 0, 0, 0); \
    acc[0][7] = __builtin_amdgcn_mfma_f32_16x16x32_bf16(_af0, P##b7, acc[0][7], 0, 0, 0); \
    acc[1][7] = __builtin_amdgcn_mfma_f32_16x16x32_bf16(_af1, P##b7, acc[1][7], 0, 0, 0); \
    accL0 = __builtin_amdgcn_mfma_f32_16x16x32_bf16(_af0, ones, accL0, 0, 0, 0); \
    accL1 = __builtin_amdgcn_mfma_f32_16x16x32_bf16(_af1, ones, accL1, 0, 0, 0); \
} while (0)

__global__ __launch_bounds__(256, 2) void k_attn(const unsigned char* __restrict__ adjp,
                                                 const float2* __restrict__ fsE,
                                                 const float2* __restrict__ fdE,
                                                 const unsigned short* __restrict__ hBT,
                                                 float* __restrict__ out) {
    __shared__ f32x4 cbuf[3584];   // 16 acc-slots * 3 partials + 8 L slots, 56 KB
    const int t = threadIdx.x;
    const int head = blockIdx.x & 3;           // XCD-pinned head
    const int n0 = (blockIdx.x >> 2) * 32;
    const int wv = t >> 6, lane = t & 63;
    const int quad = lane >> 4, nl = lane & 15;
    const int m0base = wv << 10;               // this wave's m-quarter
    const float2 es0 = fsE[(head << 12) + n0 + nl];
    const float2 es1 = fsE[(head << 12) + n0 + 16 + nl];
    const unsigned char* ap0 = adjp + ((size_t)(n0 + nl) << 9) + (m0base >> 3) + quad;
    const unsigned char* ap1 = ap0 + (16u << 9);
    const float4* fdb = (const float4*)(fdE + (head << 12) + m0base + quad * 8);
    const unsigned short* bbase = hBT + (size_t)(head * 128 + nl) * HS + quad * 8 + m0base;
    const short8 ones = __builtin_bit_cast(short8,
        (i32x4){0x3F803F80, 0x3F803F80, 0x3F803F80, 0x3F803F80});
    f32x4 acc[2][8];
    f32x4 accL0 = (f32x4){0.f, 0.f, 0.f, 0.f}, accL1 = (f32x4){0.f, 0.f, 0.f, 0.f};
#pragma unroll
    for (int rt = 0; rt < 2; rt++)
#pragma unroll
        for (int ct = 0; ct < 8; ct++) acc[rt][ct] = (f32x4){0.f, 0.f, 0.f, 0.f};
    // two pipeline stages, individually named registers (no copy chain)
    short8 Ab0, Ab1, Ab2, Ab3, Ab4, Ab5, Ab6, Ab7;
    short8 Bb0, Bb1, Bb2, Bb3, Bb4, Bb5, Bb6, Bb7;
    unsigned int Ak0, Ak1, Bk0, Bk1;
    float4 Af0, Af1, Af2, Af3, Bf0, Bf1, Bf2, Bf3;
    STAGE_LOAD(A, 0);
    STAGE_LOAD(B, 1);
    for (int mc = 0; mc < 32; mc += 2) {
        STAGE_EXEC(A);
        STAGE_LOAD(A, (mc + 2) & 31);          // wrap load harmless
        STAGE_EXEC(B);
        STAGE_LOAD(B, (mc + 3) & 31);
    }
    // ---- combine 4 m-quarters (acc slot (rt,ct) owned by wave ct&3) ----
#pragma unroll
    for (int rt = 0; rt < 2; rt++)
#pragma unroll
        for (int ct = 0; ct < 8; ct++) {
            const int owner = ct & 3;
            if (owner != wv) {
                const int j = (wv - owner - 1) & 3;
                cbuf[((rt * 8 + ct) * 3 + j) * 64 + lane] = acc[rt][ct];
            }
        }
    cbuf[3072 + wv * 64 + lane] = accL0;
    cbuf[3072 + (4 + wv) * 64 + lane] = accL1;
    __syncthreads();
#pragma unroll
    for (int rt = 0; rt < 2; rt++) {
        f32x4 Lt = (f32x4){0.f, 0.f, 0.f, 0.f};
#pragma unroll
        for (int v = 0; v < 4; v++) Lt += cbuf[3072 + (rt * 4 + v) * 64 + lane];
        float iL[4];
#pragma unroll
        for (int r = 0; r < 4; r++) iL[r] = (Lt[r] > 0.f) ? (1.0f / Lt[r]) : 0.0f;
#pragma unroll
        for (int ct = 0; ct < 8; ct++) {
            if ((ct & 3) == wv) {              // wave-uniform; ct stays constant
                f32x4 tot = acc[rt][ct];
#pragma unroll
                for (int j = 0; j < 3; j++) tot += cbuf[((rt * 8 + ct) * 3 + j) * 64 + lane];
#pragma unroll
                for (int r = 0; r < 4; r++) {
                    float v = tot[r] * iL[r];
                    v = v > 0.f ? v : (__expf(v) - 1.0f);   // ELU(alpha=1)
                    out[(size_t)(n0 + rt * 16 + quad * 4 + r) * 512
                        + head * 128 + ct * 16 + nl] = v;
                }
            }
        }
    }
}

extern "C" void kernel_launch(void* const* d_in, const int* in_sizes, int n_in,
                              void* d_out, int out_size, void* d_ws, size_t ws_size,
                              hipStream_t stream) {
    (void)in_sizes; (void)n_in; (void)out_size; (void)ws_size;
    const float* x   = (const float*)d_in[0];   // (4096,512) fp32
    const int*   adj = (const int*)d_in[1];     // (4096,4096) i32
    const float* W   = (const float*)d_in[2];   // (4,128,128) fp32
    const float* a   = (const float*)d_in[3];   // (4,256) fp32
    float* out = (float*)d_out;                 // (4096,512) fp32

    char* ws = (char*)d_ws;
    unsigned short* xbf  = (unsigned short*)(ws);             // 4096*544*2 = 4456448
    unsigned short* hBT  = (unsigned short*)(ws + 4456448);   // 4*128*4128*2 = 4227072
    unsigned short* hamT = (unsigned short*)(ws + 8683520);   // 4*128*544*2 = 557056
    unsigned char*  adjp = (unsigned char*)(ws + 9240576);    // 2 MB bitmask
    float2*         fsE  = (float2*)(ws + 11337728);          // 128 KB
    float2*         fdE  = (float2*)(ws + 11468800);          // 128 KB

    hipLaunchKernelGGL(k_prep, dim3(3200),    dim3(256), 0, stream,
                       x, W, adj, xbf, hamT, (unsigned int*)adjp);
    hipLaunchKernelGGL(k_h,    dim3(64, 4),   dim3(256), 0, stream, xbf, hamT, a, hBT, fsE, fdE);
    hipLaunchKernelGGL(k_attn, dim3(512),     dim3(256), 0, stream, adjp, fsE, fdE, hBT, out);
}

// Round 9
// 160.014 us; speedup vs baseline: 4.5535x; 1.1047x over previous
//
#include <hip/hip_runtime.h>
#include <math.h>

#define ALPHA 0.2f

// Padded strides: odd multiples of 64B lines to kill L1 set-aliasing
#define XS   544    // xbf / hamT row stride in shorts (17 lines)
#define HS   4128   // hBT col stride in shorts (129 lines)
#define HCS  66048  // 16 cols * HS

typedef __attribute__((ext_vector_type(8))) short short8;
typedef __attribute__((ext_vector_type(4))) float f32x4;
typedef __attribute__((ext_vector_type(4))) int i32x4;

__device__ __forceinline__ unsigned short f2bf(float f) {
    unsigned int x = __float_as_uint(f);
    x += 0x7fffu + ((x >> 16) & 1u);   // RNE
    return (unsigned short)(x >> 16);
}
__device__ __forceinline__ unsigned int pack_rne(float lo, float hi) {
    return (unsigned int)f2bf(lo) | ((unsigned int)f2bf(hi) << 16);
}
// truncating bf16 pack (bias cancels in w/L since L sums the same truncated w)
__device__ __forceinline__ unsigned int pack_trunc(float lo, float hi) {
    return __builtin_amdgcn_perm(__float_as_uint(hi), __float_as_uint(lo), 0x07060302u);
}
// bit j of x -> 0x0 / 0xFFFFFFFF
__device__ __forceinline__ unsigned int bitmask1(unsigned int x, int j) {
    return (unsigned int)(((int)(x << (31 - j))) >> 31);
}

// ---------------------------------------------------------------------------
// K0 (fused prep): [0,1024): x fp32->bf16 (padded rows). [1024,1152):
// hamilton transposed bf16. [1152,3200): adj -> 1-bit mask, 32/thread.
// ---------------------------------------------------------------------------
__global__ __launch_bounds__(256) void k_prep(const float* __restrict__ x,
                                              const float* __restrict__ W,
                                              const int* __restrict__ adj,
                                              unsigned short* __restrict__ xbf,
                                              unsigned short* __restrict__ hamT,
                                              unsigned int* __restrict__ adjp32) {
    const int b = blockIdx.x;
    if (b < 1024) {                       // ---- x convert: 2M elems, 8/thread
        const int gid = b * 256 + threadIdx.x;
        const int row = gid >> 6, c8 = (gid & 63) * 8;
        const float4* xp = (const float4*)x + (size_t)gid * 2;
        const float4 f0 = xp[0], f1 = xp[1];
        const uint4 o = {pack_rne(f0.x, f0.y), pack_rne(f0.z, f0.w),
                         pack_rne(f1.x, f1.y), pack_rne(f1.z, f1.w)};
        *(uint4*)(xbf + (size_t)row * XS + c8) = o;
    } else if (b < 1152) {                // ---- hamilton: sign mask 0x5390
        const int gid = (b - 1024) * 256 + threadIdx.x;    // 32768
        const int head = gid >> 13;
        const int rem  = gid & 8191;
        const int o = rem >> 6, f8 = rem & 63;
        const int ob = o >> 5, oc = o & 31;
        float v[8];
#pragma unroll
        for (int j = 0; j < 8; j++) {
            const int f = f8 * 8 + j;
            const int bq = f >> 7, f0 = f & 127;
            const float s = ((0x5390u >> ((bq << 2) | ob)) & 1u) ? -1.0f : 1.0f;
            v[j] = s * W[(head << 14) + (f0 << 7) + (((bq ^ ob) << 5) | oc)];
        }
        const uint4 pk = {pack_rne(v[0], v[1]), pack_rne(v[2], v[3]),
                          pack_rne(v[4], v[5]), pack_rne(v[6], v[7])};
        *(uint4*)(hamT + (size_t)(head * 128 + o) * XS + f8 * 8) = pk;
    } else {                              // ---- adj bit-pack: 64 MB -> 2 MB
        const int gid = (b - 1152) * 256 + threadIdx.x;    // 0..524287
        const int4* ap = (const int4*)(adj + (size_t)gid * 32);
        unsigned int u = 0;
#pragma unroll
        for (int q = 0; q < 8; q++) {
            const int4 v = ap[q];
            u |= (v.x > 0 ? 1u : 0u) << (q * 4);
            u |= (v.y > 0 ? 2u : 0u) << (q * 4);
            u |= (v.z > 0 ? 4u : 0u) << (q * 4);
            u |= (v.w > 0 ? 8u : 0u) << (q * 4);
        }
        adjp32[gid] = u;
    }
}

// ---------------------------------------------------------------------------
// K1: h = x @ ham via bf16 MFMA (passed R5/R7/R8). Block: 4 waves x 16 rows,
// 128 cols. Outputs hBT (padded col-major bf16) + fsE/fdE.
// ---------------------------------------------------------------------------
__global__ __launch_bounds__(256) void k_h(const unsigned short* __restrict__ xbf,
                                           const unsigned short* __restrict__ hamT,
                                           const float* __restrict__ a,
                                           unsigned short* __restrict__ hBT,
                                           float2* __restrict__ fsE,
                                           float2* __restrict__ fdE) {
    const int t = threadIdx.x;
    const int head = blockIdx.y;
    const int n0 = blockIdx.x * 64;
    const int wv = t >> 6, lane = t & 63;
    const int quad = lane >> 4, nl = lane & 15;
    const unsigned short* ap = xbf + (size_t)(n0 + wv * 16 + nl) * XS + quad * 8;
    const unsigned short* bp = hamT + (size_t)(head * 128 + nl) * XS + quad * 8;
    f32x4 acc[8];
#pragma unroll
    for (int ct = 0; ct < 8; ct++) acc[ct] = (f32x4){0.f, 0.f, 0.f, 0.f};
    for (int kc = 0; kc < 16; kc++) {
        const short8 af = *(const short8*)(ap + kc * 32);
#pragma unroll
        for (int ct = 0; ct < 8; ct++) {
            const short8 bf_ = *(const short8*)(bp + (size_t)ct * 16 * XS + kc * 32);
            acc[ct] = __builtin_amdgcn_mfma_f32_16x16x32_bf16(af, bf_, acc[ct], 0, 0, 0);
        }
    }
    const int rbase = n0 + wv * 16 + quad * 4;
#pragma unroll
    for (int ct = 0; ct < 8; ct++) {
        const uint2 pk = {pack_rne(acc[ct][0], acc[ct][1]), pack_rne(acc[ct][2], acc[ct][3])};
        *(uint2*)(hBT + (size_t)(head * 128 + ct * 16 + nl) * HS + rbase) = pk;
    }
    float fsr[4] = {0.f, 0.f, 0.f, 0.f}, fdr[4] = {0.f, 0.f, 0.f, 0.f};
#pragma unroll
    for (int ct = 0; ct < 8; ct++) {
        const int col = ct * 16 + nl;
        const float as = a[head * 256 + col];
        const float ad = a[head * 256 + 128 + col];
#pragma unroll
        for (int r = 0; r < 4; r++) {
            fsr[r] += acc[ct][r] * as;
            fdr[r] += acc[ct][r] * ad;
        }
    }
#pragma unroll
    for (int off = 1; off < 16; off <<= 1)
#pragma unroll
        for (int r = 0; r < 4; r++) {
            fsr[r] += __shfl_xor(fsr[r], off, 64);
            fdr[r] += __shfl_xor(fdr[r], off, 64);
        }
    if (nl == 0) {
#pragma unroll
        for (int r = 0; r < 4; r++) {
            const int n = rbase + r;
            fsE[(head << 12) + n] = make_float2(__expf(fsr[r]), __expf(ALPHA * fsr[r]));
            fdE[(head << 12) + n] = make_float2(__expf(fdr[r]), __expf(ALPHA * fdr[r]));
        }
    }
}

// ---------------------------------------------------------------------------
// K2: h' = softmax(mask(leaky(fs+fd))) @ h, fused ELU.
// 64-row blocks (4 A-frags/wave): each 16B B-load feeds 4 MFMAs, so the
// even/odd pipeline's stage exec (~700 cyc) covers L2 latency. 256 blocks =
// 1/CU, head pinned per XCD. Combine via 4 LDS reuse-rounds (24KB buf).
// All register arrays indexed by compile-time constants only (R4 lesson).
// ---------------------------------------------------------------------------
#define WELT(e1, ea, j, bits, es) \
    __uint_as_float(__float_as_uint(fmaxf((es).x * (e1), (es).y * (ea))) & bitmask1((bits), (j)))
#define WPK(f4, jb, bits, es) \
    pack_trunc(WELT((f4).x, (f4).y, (jb), (bits), (es)), \
               WELT((f4).z, (f4).w, (jb) + 1, (bits), (es)))

#define LOADM(S, mcn) do {                                                \
    const int _mo = (mcn) * 32;                                           \
    _Pragma("unroll")                                                     \
    for (int _ct = 0; _ct < 8; _ct++)                                     \
        Bst[S][_ct] = *(const short8*)(bbase + (size_t)_ct * HCS + _mo);  \
    _Pragma("unroll")                                                     \
    for (int _rt = 0; _rt < 4; _rt++) Kst[S][_rt] = ap[_rt][(mcn) * 4];   \
    _Pragma("unroll")                                                     \
    for (int _q = 0; _q < 4; _q++) Fst[S][_q] = fdb[(mcn) * 16 + _q];     \
} while (0)

#define EXECM(S) do {                                                     \
    short8 _af[4];                                                        \
    _Pragma("unroll")                                                     \
    for (int _rt = 0; _rt < 4; _rt++) {                                   \
        const i32x4 _ai = {(int)WPK(Fst[S][0], 0, Kst[S][_rt], es[_rt]),  \
                           (int)WPK(Fst[S][1], 2, Kst[S][_rt], es[_rt]),  \
                           (int)WPK(Fst[S][2], 4, Kst[S][_rt], es[_rt]),  \
                           (int)WPK(Fst[S][3], 6, Kst[S][_rt], es[_rt])}; \
        _af[_rt] = __builtin_bit_cast(short8, _ai);                       \
    }                                                                     \
    _Pragma("unroll")                                                     \
    for (int _rt = 0; _rt < 4; _rt++) {                                   \
        _Pragma("unroll")                                                 \
        for (int _ct = 0; _ct < 8; _ct++)                                 \
            acc[_rt][_ct] = __builtin_amdgcn_mfma_f32_16x16x32_bf16(      \
                _af[_rt], Bst[S][_ct], acc[_rt][_ct], 0, 0, 0);           \
        accL[_rt] = __builtin_amdgcn_mfma_f32_16x16x32_bf16(              \
            _af[_rt], ones, accL[_rt], 0, 0, 0);                          \
    }                                                                     \
} while (0)

__global__ __launch_bounds__(256, 1) void k_attn(const unsigned char* __restrict__ adjp,
                                                 const float2* __restrict__ fsE,
                                                 const float2* __restrict__ fdE,
                                                 const unsigned short* __restrict__ hBT,
                                                 float* __restrict__ out) {
    __shared__ f32x4 cbuf[1536];   // 24 KB: one rt-round of partials [ct][j][lane]
    __shared__ f32x4 Lbuf[1024];   // 16 KB: [wv*4+rt][lane]
    const int t = threadIdx.x;
    const int head = blockIdx.x & 3;           // XCD-pinned head
    const int n0 = (blockIdx.x >> 2) * 64;
    const int wv = t >> 6, lane = t & 63;
    const int quad = lane >> 4, nl = lane & 15;
    const int m0base = wv << 10;               // this wave's m-quarter
    float2 es[4];
    const unsigned char* ap[4];
#pragma unroll
    for (int rt = 0; rt < 4; rt++) {
        es[rt] = fsE[(head << 12) + n0 + rt * 16 + nl];
        ap[rt] = adjp + ((size_t)(n0 + rt * 16 + nl) << 9) + (m0base >> 3) + quad;
    }
    const float4* fdb = (const float4*)(fdE + (head << 12) + m0base + quad * 8);
    const unsigned short* bbase = hBT + (size_t)(head * 128 + nl) * HS + quad * 8 + m0base;
    const short8 ones = __builtin_bit_cast(short8,
        (i32x4){0x3F803F80, 0x3F803F80, 0x3F803F80, 0x3F803F80});
    f32x4 acc[4][8], accL[4];
#pragma unroll
    for (int rt = 0; rt < 4; rt++) {
        accL[rt] = (f32x4){0.f, 0.f, 0.f, 0.f};
#pragma unroll
        for (int ct = 0; ct < 8; ct++) acc[rt][ct] = (f32x4){0.f, 0.f, 0.f, 0.f};
    }
    short8 Bst[2][8];
    unsigned int Kst[2][4];
    float4 Fst[2][4];
    LOADM(0, 0);
    LOADM(1, 1);
    for (int mc = 0; mc < 32; mc += 2) {
        EXECM(0);
        LOADM(0, (mc + 2) & 31);               // wrap load harmless
        EXECM(1);
        LOADM(1, (mc + 3) & 31);
    }
    // ---- combine 4 m-quarters, one rt-round at a time (24 KB buf reuse) ----
#pragma unroll
    for (int rt = 0; rt < 4; rt++) Lbuf[(wv * 4 + rt) * 64 + lane] = accL[rt];
#pragma unroll
    for (int rt = 0; rt < 4; rt++) {
        if (rt > 0) __syncthreads();           // prev round's reads done
#pragma unroll
        for (int ct = 0; ct < 8; ct++) {
            const int owner = ct & 3;
            if (owner != wv) {
                const int j = (wv - owner - 1) & 3;
                cbuf[(ct * 3 + j) * 64 + lane] = acc[rt][ct];
            }
        }
        __syncthreads();
        f32x4 Lt = (f32x4){0.f, 0.f, 0.f, 0.f};
#pragma unroll
        for (int v = 0; v < 4; v++) Lt += Lbuf[(v * 4 + rt) * 64 + lane];
        float iL[4];
#pragma unroll
        for (int r = 0; r < 4; r++) iL[r] = (Lt[r] > 0.f) ? (1.0f / Lt[r]) : 0.0f;
#pragma unroll
        for (int ct = 0; ct < 8; ct++) {
            if ((ct & 3) == wv) {              // wave-uniform; ct compile-time
                f32x4 tot = acc[rt][ct];
#pragma unroll
                for (int j = 0; j < 3; j++) tot += cbuf[(ct * 3 + j) * 64 + lane];
#pragma unroll
                for (int r = 0; r < 4; r++) {
                    float v = tot[r] * iL[r];
                    v = v > 0.f ? v : (__expf(v) - 1.0f);   // ELU(alpha=1)
                    out[(size_t)(n0 + rt * 16 + quad * 4 + r) * 512
                        + head * 128 + ct * 16 + nl] = v;
                }
            }
        }
    }
}

extern "C" void kernel_launch(void* const* d_in, const int* in_sizes, int n_in,
                              void* d_out, int out_size, void* d_ws, size_t ws_size,
                              hipStream_t stream) {
    (void)in_sizes; (void)n_in; (void)out_size; (void)ws_size;
    const float* x   = (const float*)d_in[0];   // (4096,512) fp32
    const int*   adj = (const int*)d_in[1];     // (4096,4096) i32
    const float* W   = (const float*)d_in[2];   // (4,128,128) fp32
    const float* a   = (const float*)d_in[3];   // (4,256) fp32
    float* out = (float*)d_out;                 // (4096,512) fp32

    char* ws = (char*)d_ws;
    unsigned short* xbf  = (unsigned short*)(ws);             // 4096*544*2 = 4456448
    unsigned short* hBT  = (unsigned short*)(ws + 4456448);   // 4*128*4128*2 = 4227072
    unsigned short* hamT = (unsigned short*)(ws + 8683520);   // 4*128*544*2 = 557056
    unsigned char*  adjp = (unsigned char*)(ws + 9240576);    // 2 MB bitmask
    float2*         fsE  = (float2*)(ws + 11337728);          // 128 KB
    float2*         fdE  = (float2*)(ws + 11468800);          // 128 KB

    hipLaunchKernelGGL(k_prep, dim3(3200),    dim3(256), 0, stream,
                       x, W, adj, xbf, hamT, (unsigned int*)adjp);
    hipLaunchKernelGGL(k_h,    dim3(64, 4),   dim3(256), 0, stream, xbf, hamT, a, hBT, fsE, fdE);
    hipLaunchKernelGGL(k_attn, dim3(256),     dim3(256), 0, stream, adjp, fsE, fdE, hBT, out);
}